// Round 1
// baseline (13562.683 us; speedup 1.0000x reference)
//
#include <hip/hip_runtime.h>

// MatchLSTM (SNLI-style) persistent-kernel implementation, fp32.
// Grid = 256 blocks (1 per CU) x 512 threads, hand-rolled grid barrier.
// Phases: S0 weight transposes -> S1 fused embed+input projections ->
// S2 premise LSTM (64 steps) -> S3 hypothesis LSTM (32 steps) ->
// S4 attention precompute GEMMs -> S5 match-LSTM loop (32 x {q, attn, cell}) -> S6 fc.

#define NWG 256
#define TPB 512

typedef float f8v __attribute__((ext_vector_type(8)));

// ---- workspace layout (float offsets) ----
#define O_XPP      0ull          // [64][128][2048] premise input proj (+bias)
#define O_HTMW     0ull          // overlay after encoders: [32][128][2048]
#define O_HTWT     8388608ull    // [32][128][512]
#define O_WSHS     10485760ull   // [64][128][512]
#define O_XPH      16777216ull   // [32][128][2048]
#define O_HST      25165824ull   // [64][512][128]  masked premise h (k-major)
#define O_HS2      29360128ull   // [64][128][512]  masked premise h (h-major)
#define O_HTT      33554432ull   // [32][512][128]  masked hyp h (k-major)
#define O_WIHTP    35651584ull   // [300][2048] perm
#define O_WIHTH    36265984ull
#define O_WHHP2    36880384ull   // [256][512][8] per-block slices, perm
#define O_WHHH2    37928960ull
#define O_MWHH2    38977536ull
#define O_MWIHL2   40026112ull
#define O_MWIHRT   41074688ull   // [512][2048] perm
#define O_WM2      42123264ull   // [256][512][2]
#define O_WST      42385408ull   // [512][512]
#define O_WTT      42647552ull
#define O_BPP      42909696ull   // [2048] perm biases
#define O_BPH      42911744ull
#define O_BPM      42913792ull
#define O_HT2      42915840ull   // [2][128][512] encoder h double buffer
#define O_HMT2     43046912ull   // [2][128][512] match h double buffer
#define O_QBUF     43177984ull   // [128][512]
#define O_AK2      43243520ull   // [128][512]
#define O_HLAST    43309056ull   // [128][512]
#define WS_FLOATS  43374592ull

__device__ unsigned g_cnt = 0u;   // monotonic across launches (never reset)
__device__ unsigned g_gen = 0u;

struct Params {
  const int* premise; const int* plen; const int* hyp; const int* hlen;
  const float* embed;
  const float* pWih; const float* pWhh; const float* pb;
  const float* hWih; const float* hWhh; const float* hb;
  const float* mWih; const float* mWhh; const float* mb;
  const float* we; const float* Ws; const float* Wt; const float* Wm;
  const float* fcW; const float* fcb;
  float* out; float* ws;
};

// Grid barrier: monotonic epoch scheme -> safe across graph replays without
// any host-side reset (d_ws is re-poisoned; these device globals are not).
__device__ __forceinline__ void gbar(){
  __syncthreads();
  if (threadIdx.x == 0){
    __threadfence();
    unsigned snap = __hip_atomic_load(&g_gen, __ATOMIC_RELAXED, __HIP_MEMORY_SCOPE_AGENT);
    unsigned n = __hip_atomic_fetch_add(&g_cnt, 1u, __ATOMIC_ACQ_REL, __HIP_MEMORY_SCOPE_AGENT);
    if ((n & 255u) == 255u){
      __hip_atomic_store(&g_gen, snap + 1u, __ATOMIC_RELEASE, __HIP_MEMORY_SCOPE_AGENT);
    } else {
      unsigned g;
      do {
        __builtin_amdgcn_s_sleep(2);
        g = __hip_atomic_load(&g_gen, __ATOMIC_ACQUIRE, __HIP_MEMORY_SCOPE_AGENT);
      } while ((int)(g - snap) <= 0);
    }
  }
  __syncthreads();
}

__device__ __forceinline__ float sigf(float x){ return 1.0f/(1.0f + __expf(-x)); }
__device__ __forceinline__ float tanhf_(float x){ return 2.0f/(1.0f + __expf(-2.0f*x)) - 1.0f; }

__device__ __forceinline__ float wsum(float v){
  #pragma unroll
  for (int o = 32; o > 0; o >>= 1) v += __shfl_xor(v, o, 64);
  return v;
}
__device__ __forceinline__ float wmaxr(float v){
  #pragma unroll
  for (int o = 32; o > 0; o >>= 1) v = fmaxf(v, __shfl_xor(v, o, 64));
  return v;
}

struct Ctx { int wg, tid, lane, wave, kc, bh, b, ub, uh; };

// One LSTM encoder phase, T steps. Block owns perm gate cols [8*wg..8*wg+7]
// (= h cols {2wg,2wg+1} x gates i,f,g,o). Cell state c lives in a register.
__device__ void lstm_phase(const Ctx& c, int T,
    const float* __restrict__ XP,    // [T][128][2048] x@Wih.T + b (perm cols)
    const float* __restrict__ wsl,   // this block's [512][8] weight slice
    const int* __restrict__ lens,
    float* __restrict__ hbuf,        // [2][128][512] double-buffered state
    float* __restrict__ houtT,       // [T][512][128] masked h (k-major)
    float* __restrict__ hout2,       // [T][128][512] masked h (h-major) or null
    float* lds)
{
  float c_reg = 0.f;
  const int mylen = (c.tid < 256) ? lens[c.ub] : 0;
  const int hc = c.wg*2 + c.uh;
  for (int t = 0; t < T; ++t){
    const float* hin  = hbuf + (size_t)(t & 1) * 65536;
    float*       hout = hbuf + (size_t)((t + 1) & 1) * 65536;
    float acc[8];
    #pragma unroll
    for (int i = 0; i < 8; ++i) acc[i] = 0.f;
    {
      const float* hr = hin + (size_t)c.b * 512 + c.kc * 128;
      const float* wk = wsl + (size_t)c.kc * 1024;   // 128*8
      for (int k = 0; k < 128; k += 4){
        float4 h4 = *(const float4*)(hr + k);
        f8v w0 = *(const f8v*)(wk + (size_t)(k+0)*8);
        f8v w1 = *(const f8v*)(wk + (size_t)(k+1)*8);
        f8v w2 = *(const f8v*)(wk + (size_t)(k+2)*8);
        f8v w3 = *(const f8v*)(wk + (size_t)(k+3)*8);
        #pragma unroll
        for (int i = 0; i < 8; ++i)
          acc[i] += h4.x*w0[i] + h4.y*w1[i] + h4.z*w2[i] + h4.w*w3[i];
      }
    }
    #pragma unroll
    for (int i = 0; i < 8; ++i) lds[(c.kc*8 + i)*128 + c.b] = acc[i];
    __syncthreads();
    if (c.tid < 256){
      const float* xp = XP + ((size_t)t*128 + c.ub)*2048 + c.wg*8 + c.uh*4;
      float4 x4 = *(const float4*)xp;
      float gi = x4.x, gf = x4.y, gg = x4.z, go = x4.w;
      #pragma unroll
      for (int kk = 0; kk < 4; ++kk){
        gi += lds[(kk*8 + c.uh*4 + 0)*128 + c.ub];
        gf += lds[(kk*8 + c.uh*4 + 1)*128 + c.ub];
        gg += lds[(kk*8 + c.uh*4 + 2)*128 + c.ub];
        go += lds[(kk*8 + c.uh*4 + 3)*128 + c.ub];
      }
      float iv = sigf(gi), fv = sigf(gf), gv = tanhf_(gg), ov = sigf(go);
      c_reg = fv * c_reg + iv * gv;
      float hv = ov * tanhf_(c_reg);
      hout[(size_t)c.ub * 512 + hc] = hv;                       // unmasked recurrence
      float hm = (t < mylen) ? hv : 0.f;                        // masked outputs
      houtT[((size_t)t*512 + hc)*128 + c.ub] = hm;
      if (hout2) hout2[((size_t)t*128 + c.ub)*512 + hc] = hm;
    }
    gbar();
  }
}

__global__ __launch_bounds__(TPB, 2) void mlstm(Params p){
  const int wg = blockIdx.x, tid = threadIdx.x;
  const int lane = tid & 63, wave = tid >> 6;
  const int gtid = wg * TPB + tid;
  const int gwave = wg * 8 + wave;
  const int kc = wave >> 1, bh = wave & 1;
  const int b  = bh * 64 + lane;
  const int ub = tid & 127, uh = (tid >> 7) & 1;
  __shared__ float lds[4224];   // [0..4095] GEMM partials, [4096..4223] attention

  float* const ws    = p.ws;
  float* const XPp   = ws + O_XPP;
  float* const XPh   = ws + O_XPH;
  float* const htmW  = ws + O_HTMW;
  float* const htWt  = ws + O_HTWT;
  float* const Ws_hs = ws + O_WSHS;
  float* const h_sT  = ws + O_HST;
  float* const h_s2  = ws + O_HS2;
  float* const h_tT  = ws + O_HTT;
  float* const WihTp = ws + O_WIHTP;
  float* const WihTh = ws + O_WIHTH;
  float* const WhhP2 = ws + O_WHHP2;
  float* const WhhH2 = ws + O_WHHH2;
  float* const mWhh2 = ws + O_MWHH2;
  float* const mWihL2= ws + O_MWIHL2;
  float* const mWihRT= ws + O_MWIHRT;
  float* const Wm2   = ws + O_WM2;
  float* const WsT   = ws + O_WST;
  float* const WtT   = ws + O_WTT;
  float* const bpP   = ws + O_BPP;
  float* const bpH   = ws + O_BPH;
  float* const bpM   = ws + O_BPM;
  float* const hT2   = ws + O_HT2;
  float* const hmT2  = ws + O_HMT2;
  float* const qbuf  = ws + O_QBUF;
  float* const ak2   = ws + O_AK2;
  float* const hlast = ws + O_HLAST;

  // ---------------- S0: weight transposes / permutations, state zero ----------------
  // gate-column permutation: perm col jp -> orig col oc = (jp&3)*512 + (jp>>2)
  for (int idx = gtid; idx < 300*2048; idx += NWG*TPB){
    int e = idx >> 11, jp = idx & 2047;
    int oc = (jp & 3) * 512 + (jp >> 2);
    WihTp[idx] = p.pWih[(size_t)oc*300 + e];
    WihTh[idx] = p.hWih[(size_t)oc*300 + e];
  }
  for (int idx = gtid; idx < 256*512*8; idx += NWG*TPB){
    int cc = idx & 7, k = (idx >> 3) & 511, wgi = idx >> 12;
    int jp = wgi*8 + cc;
    int oc = (jp & 3) * 512 + (jp >> 2);
    WhhP2[idx]  = p.pWhh[(size_t)oc*512 + k];
    WhhH2[idx]  = p.hWhh[(size_t)oc*512 + k];
    mWhh2[idx]  = p.mWhh[(size_t)oc*512 + k];
    mWihL2[idx] = p.mWih[(size_t)oc*1024 + k];          // left half (a_k)
  }
  for (int idx = gtid; idx < 512*2048; idx += NWG*TPB){
    int k = idx >> 11, jp = idx & 2047;
    int oc = (jp & 3) * 512 + (jp >> 2);
    mWihRT[idx] = p.mWih[(size_t)oc*1024 + 512 + k];    // right half (h_t)
  }
  for (int idx = gtid; idx < 256*512*2; idx += NWG*TPB){
    int cc = idx & 1, k = (idx >> 1) & 511, wgi = idx >> 10;
    Wm2[idx] = p.Wm[(size_t)(wgi*2 + cc)*512 + k];
  }
  for (int idx = gtid; idx < 512*512; idx += NWG*TPB){
    int k = idx >> 9, h = idx & 511;
    WsT[idx] = p.Ws[(size_t)h*512 + k];
    WtT[idx] = p.Wt[(size_t)h*512 + k];
  }
  for (int idx = gtid; idx < 2048; idx += NWG*TPB){
    int oc = (idx & 3) * 512 + (idx >> 2);
    bpP[idx] = p.pb[oc]; bpH[idx] = p.hb[oc]; bpM[idx] = p.mb[oc];
  }
  for (int idx = gtid; idx < 65536; idx += NWG*TPB){ hT2[idx] = 0.f; hmT2[idx] = 0.f; }
  gbar();

  // ---------------- S1: XP = embed[tokens] @ WihT + bias (fused gather) ----------------
  for (int task = gwave; task < 6144; task += NWG*8){
    const bool prem = task < 4096;
    const int t2 = prem ? task : task - 4096;
    const int rb = t2 >> 2, cb = t2 & 3;
    const int r0 = rb * 8;
    const int* toks = prem ? p.premise : p.hyp;
    const float* wT = prem ? WihTp : WihTh;
    const float* bias = prem ? bpP : bpH;
    float* outp = prem ? XPp : XPh;
    const int j0 = cb * 512 + lane * 8;
    const float* xr[8];
    #pragma unroll
    for (int r = 0; r < 8; ++r) xr[r] = p.embed + (size_t)toks[r0 + r] * 300;
    f8v bias8 = *(const f8v*)(bias + j0);
    float acc[8][8];
    #pragma unroll
    for (int r = 0; r < 8; ++r){
      #pragma unroll
      for (int i = 0; i < 8; ++i) acc[r][i] = 0.f;
    }
    for (int e = 0; e < 300; ++e){
      f8v w8 = *(const f8v*)(wT + (size_t)e * 2048 + j0);
      #pragma unroll
      for (int r = 0; r < 8; ++r){
        float xv = xr[r][e];
        #pragma unroll
        for (int i = 0; i < 8; ++i) acc[r][i] += xv * w8[i];
      }
    }
    #pragma unroll
    for (int r = 0; r < 8; ++r){
      f8v o8;
      #pragma unroll
      for (int i = 0; i < 8; ++i) o8[i] = acc[r][i] + bias8[i];
      *(f8v*)(outp + (size_t)(r0 + r) * 2048 + j0) = o8;
    }
  }
  gbar();

  // ---------------- S2/S3: encoder LSTMs ----------------
  Ctx cx{wg, tid, lane, wave, kc, bh, b, ub, uh};
  lstm_phase(cx, 64, XPp, WhhP2 + (size_t)wg*4096, p.plen, hT2, h_sT, h_s2, lds);
  for (int idx = gtid; idx < 65536; idx += NWG*TPB) hT2[idx] = 0.f;  // reset state buf0
  gbar();
  lstm_phase(cx, 32, XPh, WhhH2 + (size_t)wg*4096, p.hlen, hT2, h_tT, nullptr, lds);

  // ---------------- S4: Ws_hs, htWt, htmW (overlaid on XPp region) ----------------
  for (int task = gwave; task < 3584; task += NWG*8){
    const float* src; const float* wT; const float* bias; float* outp;
    int rb, cb, cols;
    if (task < 1024){ rb = task;        cb = 0;            src = h_sT; wT = WsT;    bias = nullptr; outp = Ws_hs; cols = 512; }
    else if (task < 1536){ rb = task-1024; cb = 0;         src = h_tT; wT = WtT;    bias = nullptr; outp = htWt;  cols = 512; }
    else { int t2 = task - 1536; rb = t2 >> 2; cb = t2 & 3; src = h_tT; wT = mWihRT; bias = bpM;    outp = htmW;  cols = 2048; }
    const int r0 = rb * 8;
    const int j0 = cb * 512 + lane * 8;
    const float* xr[8];
    #pragma unroll
    for (int r = 0; r < 8; ++r){
      int row = r0 + r;
      xr[r] = src + (size_t)(row >> 7) * 65536 + (row & 127);  // [t][k][b], stride 128 in k
    }
    f8v bias8 = {0,0,0,0,0,0,0,0};
    if (bias) bias8 = *(const f8v*)(bias + j0);
    float acc[8][8];
    #pragma unroll
    for (int r = 0; r < 8; ++r){
      #pragma unroll
      for (int i = 0; i < 8; ++i) acc[r][i] = 0.f;
    }
    for (int k = 0; k < 512; ++k){
      f8v w8 = *(const f8v*)(wT + (size_t)k * cols + j0);
      #pragma unroll
      for (int r = 0; r < 8; ++r){
        float xv = xr[r][(size_t)k * 128];
        #pragma unroll
        for (int i = 0; i < 8; ++i) acc[r][i] += xv * w8[i];
      }
    }
    #pragma unroll
    for (int r = 0; r < 8; ++r){
      f8v o8;
      #pragma unroll
      for (int i = 0; i < 8; ++i) o8[i] = acc[r][i] + bias8[i];
      *(f8v*)(outp + (size_t)(r0 + r) * (size_t)cols + j0) = o8;
    }
  }
  gbar();

  // ---------------- S5: match-LSTM loop ----------------
  float cm_reg = 0.f, hl_reg = 0.f;
  const int hyplen_u = (tid < 256) ? p.hlen[ub] : 0;
  const float* mLsl = mWihL2 + (size_t)wg*4096;
  const float* mHsl = mWhh2  + (size_t)wg*4096;
  const float* wmsl = Wm2    + (size_t)wg*1024;
  const int hc = wg*2 + uh;

  for (int k = 0; k < 32; ++k){
    const float* hmin  = hmT2 + (size_t)(k & 1) * 65536;
    float*       hmout = hmT2 + (size_t)((k + 1) & 1) * 65536;

    // --- A: q = htWt[k] + h_m @ Wm.T   (block owns h cols {2wg,2wg+1})
    {
      float a0 = 0.f, a1 = 0.f;
      const float* hr = hmin + (size_t)b * 512 + kc * 128;
      const float* wk = wmsl + (size_t)kc * 256;   // 128*2
      for (int kk = 0; kk < 128; kk += 4){
        float4 h4 = *(const float4*)(hr + kk);
        float2 w0 = *(const float2*)(wk + (kk+0)*2);
        float2 w1 = *(const float2*)(wk + (kk+1)*2);
        float2 w2 = *(const float2*)(wk + (kk+2)*2);
        float2 w3 = *(const float2*)(wk + (kk+3)*2);
        a0 += h4.x*w0.x + h4.y*w1.x + h4.z*w2.x + h4.w*w3.x;
        a1 += h4.x*w0.y + h4.y*w1.y + h4.z*w2.y + h4.w*w3.y;
      }
      lds[(kc*2 + 0)*128 + b] = a0;
      lds[(kc*2 + 1)*128 + b] = a1;
      __syncthreads();
      if (tid < 256){
        float s = lds[(0*2+uh)*128+ub] + lds[(1*2+uh)*128+ub]
                + lds[(2*2+uh)*128+ub] + lds[(3*2+uh)*128+ub];
        qbuf[(size_t)ub*512 + hc] = s + htWt[((size_t)k*128 + ub)*512 + hc];
      }
    }
    gbar();

    // --- BC: attention scores + softmax + a_k (one block per batch element)
    if (wg < 128){
      const int bb = wg;
      const float* qb = qbuf + (size_t)bb*512 + lane*8;
      float4 q0 = *(const float4*)qb;
      float4 q1 = *(const float4*)(qb + 4);
      float4 e0 = *(const float4*)(p.we + lane*8);
      float4 e1 = *(const float4*)(p.we + lane*8 + 4);
      #pragma unroll
      for (int si = 0; si < 8; ++si){
        int s = wave*8 + si;
        const float* wsr = Ws_hs + ((size_t)s*128 + bb)*512 + lane*8;
        float4 s0 = *(const float4*)wsr;
        float4 s1 = *(const float4*)(wsr + 4);
        float v = tanhf_(s0.x + q0.x)*e0.x + tanhf_(s0.y + q0.y)*e0.y
                + tanhf_(s0.z + q0.z)*e0.z + tanhf_(s0.w + q0.w)*e0.w
                + tanhf_(s1.x + q1.x)*e1.x + tanhf_(s1.y + q1.y)*e1.y
                + tanhf_(s1.z + q1.z)*e1.z + tanhf_(s1.w + q1.w)*e1.w;
        v = wsum(v);
        if (lane == 0) lds[4096 + s] = v;
      }
      __syncthreads();
      if (wave == 0){
        float v = lds[4096 + lane];
        float m = wmaxr(v);
        float ex = __expf(v - m);
        float sm = wsum(ex);
        lds[4160 + lane] = ex / sm;
      }
      __syncthreads();
      {
        float acc = 0.f;
        const float* hsb = h_s2 + (size_t)bb*512 + tid;
        #pragma unroll 4
        for (int s = 0; s < 64; s += 4){
          float4 al = *(const float4*)(lds + 4160 + s);
          acc += al.x * hsb[(size_t)(s+0)*65536]
               + al.y * hsb[(size_t)(s+1)*65536]
               + al.z * hsb[(size_t)(s+2)*65536]
               + al.w * hsb[(size_t)(s+3)*65536];
        }
        ak2[(size_t)bb*512 + tid] = acc;
      }
    }
    gbar();

    // --- D: g = htmW[k] + a_k @ mWihL.T + h_m @ mWhh.T ; cell update
    {
      float acc[8];
      #pragma unroll
      for (int i = 0; i < 8; ++i) acc[i] = 0.f;
      {
        const float* ar = ak2 + (size_t)b * 512 + kc * 128;
        const float* wk = mLsl + (size_t)kc * 1024;
        for (int kk = 0; kk < 128; kk += 4){
          float4 h4 = *(const float4*)(ar + kk);
          f8v w0 = *(const f8v*)(wk + (size_t)(kk+0)*8);
          f8v w1 = *(const f8v*)(wk + (size_t)(kk+1)*8);
          f8v w2 = *(const f8v*)(wk + (size_t)(kk+2)*8);
          f8v w3 = *(const f8v*)(wk + (size_t)(kk+3)*8);
          #pragma unroll
          for (int i = 0; i < 8; ++i)
            acc[i] += h4.x*w0[i] + h4.y*w1[i] + h4.z*w2[i] + h4.w*w3[i];
        }
      }
      {
        const float* hr = hmin + (size_t)b * 512 + kc * 128;
        const float* wk = mHsl + (size_t)kc * 1024;
        for (int kk = 0; kk < 128; kk += 4){
          float4 h4 = *(const float4*)(hr + kk);
          f8v w0 = *(const f8v*)(wk + (size_t)(kk+0)*8);
          f8v w1 = *(const f8v*)(wk + (size_t)(kk+1)*8);
          f8v w2 = *(const f8v*)(wk + (size_t)(kk+2)*8);
          f8v w3 = *(const f8v*)(wk + (size_t)(kk+3)*8);
          #pragma unroll
          for (int i = 0; i < 8; ++i)
            acc[i] += h4.x*w0[i] + h4.y*w1[i] + h4.z*w2[i] + h4.w*w3[i];
        }
      }
      #pragma unroll
      for (int i = 0; i < 8; ++i) lds[(kc*8 + i)*128 + b] = acc[i];
      __syncthreads();
      if (tid < 256){
        const float* xp = htmW + ((size_t)k*128 + ub)*2048 + wg*8 + uh*4;
        float4 x4 = *(const float4*)xp;
        float gi = x4.x, gf = x4.y, gg = x4.z, go = x4.w;
        #pragma unroll
        for (int kk = 0; kk < 4; ++kk){
          gi += lds[(kk*8 + uh*4 + 0)*128 + ub];
          gf += lds[(kk*8 + uh*4 + 1)*128 + ub];
          gg += lds[(kk*8 + uh*4 + 2)*128 + ub];
          go += lds[(kk*8 + uh*4 + 3)*128 + ub];
        }
        float iv = sigf(gi), fv = sigf(gf), gv = tanhf_(gg), ov = sigf(go);
        cm_reg = fv * cm_reg + iv * gv;
        float hv = ov * tanhf_(cm_reg);
        hmout[(size_t)ub*512 + hc] = hv;
        if (k + 1 == hyplen_u) hl_reg = hv;
      }
    }
    gbar();
  }

  if (tid < 256) hlast[(size_t)ub*512 + hc] = hl_reg;
  gbar();

  // ---------------- S6: fc on block 0 ----------------
  if (wg == 0){
    for (int o = wave; o < 384; o += 8){
      int bb = o / 3, cls = o - bb*3;
      const float* hr = hlast + (size_t)bb*512 + lane*8;
      const float* wr = p.fcW + (size_t)cls*512 + lane*8;
      float4 h0 = *(const float4*)hr, h1 = *(const float4*)(hr + 4);
      float4 w0 = *(const float4*)wr, w1 = *(const float4*)(wr + 4);
      float v = h0.x*w0.x + h0.y*w0.y + h0.z*w0.z + h0.w*w0.w
              + h1.x*w1.x + h1.y*w1.y + h1.z*w1.z + h1.w*w1.w;
      v = wsum(v);
      if (lane == 0) p.out[o] = v + p.fcb[cls];
    }
  }
}

extern "C" void kernel_launch(void* const* d_in, const int* in_sizes, int n_in,
                              void* d_out, int out_size, void* d_ws, size_t ws_size,
                              hipStream_t stream) {
  if (ws_size < WS_FLOATS * sizeof(float)) return;  // fail clean (wrong answer), not OOB
  Params prm;
  prm.premise = (const int*)d_in[0];
  prm.plen    = (const int*)d_in[1];
  prm.hyp     = (const int*)d_in[2];
  prm.hlen    = (const int*)d_in[3];
  prm.embed   = (const float*)d_in[4];
  prm.pWih    = (const float*)d_in[5];
  prm.pWhh    = (const float*)d_in[6];
  prm.pb      = (const float*)d_in[7];
  prm.hWih    = (const float*)d_in[8];
  prm.hWhh    = (const float*)d_in[9];
  prm.hb      = (const float*)d_in[10];
  prm.mWih    = (const float*)d_in[11];
  prm.mWhh    = (const float*)d_in[12];
  prm.mb      = (const float*)d_in[13];
  prm.we      = (const float*)d_in[14];
  prm.Ws      = (const float*)d_in[15];
  prm.Wt      = (const float*)d_in[16];
  prm.Wm      = (const float*)d_in[17];
  prm.fcW     = (const float*)d_in[18];
  prm.fcb     = (const float*)d_in[19];
  prm.out     = (float*)d_out;
  prm.ws      = (float*)d_ws;
  mlstm<<<dim3(NWG), dim3(TPB), 0, stream>>>(prm);
}

// Round 2
// 5925.328 us; speedup vs baseline: 2.2889x; 2.2889x over previous
//
#include <hip/hip_runtime.h>

// MatchLSTM persistent-kernel, fp32, round 2.
// Key change vs R1: two-tier grid barriers. The ~193 in-loop barriers are
// fence-free (no buffer_inv/buffer_wbl2) so read-only weight/attention streams
// stay L2-resident; loop-carried state (h, q, a_k) moves through system-scope
// (sc0 sc1) loads/stores that bypass L2 (coherent at L3). Recurrent GEMMs are
// re-decomposed as (128 gate-cols x 8 batch) per block so the per-block state
// slice is 16-32KB, staged once into LDS per step.

#define NWG 256
#define TPB 512

typedef float f8v __attribute__((ext_vector_type(8)));

// ---- workspace layout (float offsets) ----
#define O_XPP      0ull          // [64][128][2048] premise input proj (+bias)
#define O_HTMW     0ull          // overlay after encoders: [32][128][2048]
#define O_HTWT     8388608ull    // [32][128][512]
#define O_WSHS     10485760ull   // [64][128][512]
#define O_XPH      16777216ull   // [32][128][2048]
#define O_HST      25165824ull   // [64][512][128]  masked premise h (k-major)
#define O_HS2      29360128ull   // [64][128][512]  masked premise h (h-major)
#define O_HTT      33554432ull   // [32][512][128]  masked hyp h (k-major)
#define O_WIHTP    35651584ull   // [300][2048] perm
#define O_WIHTH    36265984ull
#define O_WHHPP    36880384ull   // [1024 pair-rows][512 k][2] premise Whh
#define O_WHHPH    37928960ull
#define O_DW       38977536ull   // [1024 pair-rows][1024 k][2] match (mWihL | mWhh)
#define O_WST      41074688ull   // [512][512] k-major
#define O_WTT      41336832ull
#define O_MWIHRT   41598976ull   // [512][2048] perm
#define O_BPP      42647552ull   // [2048] perm biases
#define O_BPH      42649600ull
#define O_BPM      42651648ull
#define O_HT2      42653696ull   // [2][128][512] encoder h double buffer (coherent)
#define O_HMT2     42784768ull   // [2][128][512] match h double buffer (coherent)
#define O_QBUF     42915840ull   // [128][512] (coherent)
#define O_AK2      42981376ull   // [128][512] (coherent)
#define O_HLAST    43046912ull   // [128][512]
#define WS_FLOATS  43112448ull

__device__ unsigned g_cnt = 0u;   // monotonic across launches (never reset)
__device__ unsigned g_gen = 0u;

struct Params {
  const int* premise; const int* plen; const int* hyp; const int* hlen;
  const float* embed;
  const float* pWih; const float* pWhh; const float* pb;
  const float* hWih; const float* hWhh; const float* hb;
  const float* mWih; const float* mWhh; const float* mb;
  const float* we; const float* Ws; const float* Wt; const float* Wm;
  const float* fcW; const float* fcb;
  float* out; float* ws;
};

// ---- coherent (system-scope, L2-bypassing) accessors for mutable state ----
__device__ __forceinline__ float2 sysld2(const float* p){
  unsigned long long u = __hip_atomic_load((const unsigned long long*)p,
      __ATOMIC_RELAXED, __HIP_MEMORY_SCOPE_SYSTEM);
  union { unsigned long long u; float2 f; } c; c.u = u; return c.f;
}
__device__ __forceinline__ void sysst(float* p, float v){
  union { float f; unsigned u; } c; c.f = v;
  __hip_atomic_store((unsigned*)p, c.u, __ATOMIC_RELAXED, __HIP_MEMORY_SCOPE_SYSTEM);
}

// Heavy barrier (phase boundaries only): flush + invalidate L2 so normal
// loads/stores become grid-visible. Proven correct in R1.
__device__ __forceinline__ void gbarH(){
  __syncthreads();
  if (threadIdx.x == 0){
    __threadfence();
    unsigned snap = __hip_atomic_load(&g_gen, __ATOMIC_RELAXED, __HIP_MEMORY_SCOPE_AGENT);
    unsigned n = __hip_atomic_fetch_add(&g_cnt, 1u, __ATOMIC_ACQ_REL, __HIP_MEMORY_SCOPE_AGENT);
    if ((n & 255u) == 255u){
      __hip_atomic_store(&g_gen, snap + 1u, __ATOMIC_RELEASE, __HIP_MEMORY_SCOPE_AGENT);
    } else {
      unsigned g;
      do {
        __builtin_amdgcn_s_sleep(2);
        g = __hip_atomic_load(&g_gen, __ATOMIC_ACQUIRE, __HIP_MEMORY_SCOPE_AGENT);
      } while ((int)(g - snap) <= 0);
    }
  }
  __syncthreads();
}

// Light barrier (in-loop): NO cache maintenance. Safe because (a) __syncthreads
// drains each wave's outstanding vmem (compiler emits s_waitcnt vmcnt(0) before
// s_barrier), so all system-scope write-through stores have reached the
// coherence point before arrival; (b) all cross-block state is accessed ONLY
// via sysld2/sysst (bypass L2); read-only data untouched -> L2 stays warm.
__device__ __forceinline__ void gbarL(){
  __syncthreads();
  if (threadIdx.x == 0){
    __atomic_signal_fence(__ATOMIC_SEQ_CST);
    unsigned snap = __hip_atomic_load(&g_gen, __ATOMIC_RELAXED, __HIP_MEMORY_SCOPE_SYSTEM);
    unsigned n = __hip_atomic_fetch_add(&g_cnt, 1u, __ATOMIC_RELAXED, __HIP_MEMORY_SCOPE_SYSTEM);
    if ((n & 255u) == 255u){
      __hip_atomic_store(&g_gen, snap + 1u, __ATOMIC_RELAXED, __HIP_MEMORY_SCOPE_SYSTEM);
    } else {
      unsigned g;
      do {
        __builtin_amdgcn_s_sleep(1);
        g = __hip_atomic_load(&g_gen, __ATOMIC_RELAXED, __HIP_MEMORY_SCOPE_SYSTEM);
      } while ((int)(g - snap) <= 0);
    }
    __atomic_signal_fence(__ATOMIC_SEQ_CST);
  }
  __syncthreads();
}

__device__ __forceinline__ float sigf(float x){ return 1.0f/(1.0f + __expf(-x)); }
__device__ __forceinline__ float tanhf_(float x){ return 2.0f/(1.0f + __expf(-2.0f*x)) - 1.0f; }

__device__ __forceinline__ float wsum(float v){
  #pragma unroll
  for (int o = 32; o > 0; o >>= 1) v += __shfl_xor(v, o, 64);
  return v;
}
__device__ __forceinline__ float wmaxr(float v){
  #pragma unroll
  for (int o = 32; o > 0; o >>= 1) v = fmaxf(v, __shfl_xor(v, o, 64));
  return v;
}

// One encoder LSTM. Block = (cg: 32 h-cols, bg: 8 batch). Thread (b8,hc32,gp)
// owns gates {gp*2, gp*2+1} of (b,hc); full K=512 dot from LDS-staged h.
__device__ void lstm_enc(int tid, int cg, int bg, int T,
    const float* __restrict__ XP, const float* __restrict__ WPair,
    const int* __restrict__ lens, float* hbuf,
    float* __restrict__ houtT, float* __restrict__ hout2, float* lds)
{
  const int b8 = tid & 7, hc32 = (tid >> 3) & 31, gp = tid >> 8;
  const int b = bg*8 + b8, hc = cg*32 + hc32;
  const float* wrow = WPair + (size_t)(hc*2 + gp) * 1024;   // [512][2]
  const int mylen = lens[b];
  const int sb = tid >> 6, sk = (tid & 63) * 8;
  float* stage = lds;            // [8][516] padded (516%32==4 -> conflict-free)
  float* xch   = lds + 8*516;    // [256][2]
  float c_reg = 0.f;

  for (int t = 0; t < T; ++t){
    const float* hin  = hbuf + (size_t)(t & 1) * 65536;
    float*       hout = hbuf + (size_t)((t + 1) & 1) * 65536;
    { // cooperative coherent load of h[bg*8..+8][512] -> LDS (16KB)
      const float* src = hin + (size_t)(bg*8 + sb)*512 + sk;
      float2 v0 = sysld2(src), v1 = sysld2(src+2), v2 = sysld2(src+4), v3 = sysld2(src+6);
      float* dst = stage + sb*516 + sk;
      dst[0]=v0.x; dst[1]=v0.y; dst[2]=v1.x; dst[3]=v1.y;
      dst[4]=v2.x; dst[5]=v2.y; dst[6]=v3.x; dst[7]=v3.y;
    }
    __syncthreads();
    float a0 = 0.f, a1 = 0.f;
    const float* hr = stage + b8*516;
    #pragma unroll 2
    for (int k = 0; k < 512; k += 4){
      float4 h4 = *(const float4*)(hr + k);
      float4 wA = *(const float4*)(wrow + k*2);
      float4 wB = *(const float4*)(wrow + k*2 + 4);
      a0 += h4.x*wA.x + h4.y*wA.z + h4.z*wB.x + h4.w*wB.z;
      a1 += h4.x*wA.y + h4.y*wA.w + h4.z*wB.y + h4.w*wB.w;
    }
    float2 xg = *(const float2*)(XP + ((size_t)t*128 + b)*2048 + hc*4 + gp*2);
    a0 += xg.x; a1 += xg.y;
    if (gp == 1){ xch[(b8*32+hc32)*2+0] = a0; xch[(b8*32+hc32)*2+1] = a1; }
    __syncthreads();
    if (gp == 0){
      float gg = xch[(b8*32+hc32)*2+0], go = xch[(b8*32+hc32)*2+1];
      float iv = sigf(a0), fv = sigf(a1), gv = tanhf_(gg), ov = sigf(go);
      c_reg = fv * c_reg + iv * gv;
      float hv = ov * tanhf_(c_reg);
      sysst(hout + (size_t)b*512 + hc, hv);          // coherent recurrence state
      float hm = (t < mylen) ? hv : 0.f;             // masked outputs (normal)
      houtT[((size_t)t*512 + hc)*128 + b] = hm;
      if (hout2) hout2[((size_t)t*128 + b)*512 + hc] = hm;
    }
    gbarL();
  }
}

__global__ __launch_bounds__(TPB, 2) void mlstm(Params p){
  const int wg = blockIdx.x, tid = threadIdx.x;
  const int lane = tid & 63, wave = tid >> 6;
  const int gtid = wg * TPB + tid;
  const int gwave = wg * 8 + wave;
  const int cg = wg & 15, bg = wg >> 4;   // col-group / batch-group roles
  __shared__ float lds[8736];             // D: [8][1028] + xch 512

  float* const ws     = p.ws;
  float* const XPp    = ws + O_XPP;
  float* const XPh    = ws + O_XPH;
  float* const htmW   = ws + O_HTMW;
  float* const htWt   = ws + O_HTWT;
  float* const Ws_hs  = ws + O_WSHS;
  float* const h_sT   = ws + O_HST;
  float* const h_s2   = ws + O_HS2;
  float* const h_tT   = ws + O_HTT;
  float* const WihTp  = ws + O_WIHTP;
  float* const WihTh  = ws + O_WIHTH;
  float* const WhhPP  = ws + O_WHHPP;
  float* const WhhPH  = ws + O_WHHPH;
  float* const DW     = ws + O_DW;
  float* const WsT    = ws + O_WST;
  float* const WtT    = ws + O_WTT;
  float* const mWihRT = ws + O_MWIHRT;
  float* const bpP    = ws + O_BPP;
  float* const bpH    = ws + O_BPH;
  float* const bpM    = ws + O_BPM;
  float* const hT2    = ws + O_HT2;
  float* const hmT2   = ws + O_HMT2;
  float* const qbuf   = ws + O_QBUF;
  float* const ak2    = ws + O_AK2;
  float* const hlast  = ws + O_HLAST;

  // ---------------- S0: weight layout transforms ----------------
  // perm col jp = hc*4 + gate  <->  orig col oc = gate*512 + hc
  for (int idx = gtid; idx < 300*2048; idx += NWG*TPB){
    int e = idx >> 11, jp = idx & 2047;
    int oc = (jp & 3) * 512 + (jp >> 2);
    WihTp[idx] = p.pWih[(size_t)oc*300 + e];
    WihTh[idx] = p.hWih[(size_t)oc*300 + e];
  }
  // paired k-major recurrent weights: [pair p=hc*2+gp][k][g], gate=gp*2+g
  for (int idx = gtid; idx < 1024*512*2; idx += NWG*TPB){
    int g = idx & 1, k = (idx >> 1) & 511, pp = idx >> 10;
    int hc = pp >> 1, gp = pp & 1, oc = (gp*2+g)*512 + hc;
    WhhPP[idx] = p.pWhh[(size_t)oc*512 + k];
    WhhPH[idx] = p.hWhh[(size_t)oc*512 + k];
  }
  // match cell weights: k<512 -> mWih left half (a_k), k>=512 -> mWhh (h_m)
  for (int idx = gtid; idx < 1024*1024*2; idx += NWG*TPB){
    int g = idx & 1, k = (idx >> 1) & 1023, pp = idx >> 11;
    int hc = pp >> 1, gp = pp & 1, oc = (gp*2+g)*512 + hc;
    DW[idx] = (k < 512) ? p.mWih[(size_t)oc*1024 + k]
                        : p.mWhh[(size_t)oc*512 + (k - 512)];
  }
  for (int idx = gtid; idx < 512*512; idx += NWG*TPB){
    int k = idx >> 9, h = idx & 511;
    WsT[idx] = p.Ws[(size_t)h*512 + k];
    WtT[idx] = p.Wt[(size_t)h*512 + k];
  }
  for (int idx = gtid; idx < 512*2048; idx += NWG*TPB){
    int k = idx >> 11, jp = idx & 2047;
    int oc = (jp & 3) * 512 + (jp >> 2);
    mWihRT[idx] = p.mWih[(size_t)oc*1024 + 512 + k];
  }
  for (int idx = gtid; idx < 2048; idx += NWG*TPB){
    int oc = (idx & 3) * 512 + (idx >> 2);
    bpP[idx] = p.pb[oc]; bpH[idx] = p.hb[oc]; bpM[idx] = p.mb[oc];
  }
  for (int idx = gtid; idx < 131072; idx += NWG*TPB){ hT2[idx] = 0.f; hmT2[idx] = 0.f; }
  gbarH();

  // ---------------- S1: XP = embed[tokens] @ WihT + bias ----------------
  // cb-outer task order so concurrent blocks share one weight column slice.
  for (int task = gwave; task < 6144; task += NWG*8){
    const bool prem = task < 4096;
    int rb, cb;
    if (prem){ cb = task >> 10; rb = task & 1023; }
    else { int t2 = task - 4096; cb = t2 >> 9; rb = t2 & 511; }
    const int r0 = rb * 8;
    const int* toks = prem ? p.premise : p.hyp;
    const float* wT = prem ? WihTp : WihTh;
    const float* bias = prem ? bpP : bpH;
    float* outp = prem ? XPp : XPh;
    const int j0 = cb * 512 + lane * 8;
    const float* xr[8];
    #pragma unroll
    for (int r = 0; r < 8; ++r) xr[r] = p.embed + (size_t)toks[r0 + r] * 300;
    f8v bias8 = *(const f8v*)(bias + j0);
    float acc[8][8];
    #pragma unroll
    for (int r = 0; r < 8; ++r){
      #pragma unroll
      for (int i = 0; i < 8; ++i) acc[r][i] = 0.f;
    }
    for (int e = 0; e < 300; ++e){
      f8v w8 = *(const f8v*)(wT + (size_t)e * 2048 + j0);
      #pragma unroll
      for (int r = 0; r < 8; ++r){
        float xv = xr[r][e];
        #pragma unroll
        for (int i = 0; i < 8; ++i) acc[r][i] += xv * w8[i];
      }
    }
    #pragma unroll
    for (int r = 0; r < 8; ++r){
      f8v o8;
      #pragma unroll
      for (int i = 0; i < 8; ++i) o8[i] = acc[r][i] + bias8[i];
      *(f8v*)(outp + (size_t)(r0 + r) * 2048 + j0) = o8;
    }
  }
  gbarH();

  // ---------------- S2/S3: encoder LSTMs ----------------
  lstm_enc(tid, cg, bg, 64, XPp, WhhPP, p.plen, hT2, h_sT, h_s2, lds);
  for (int idx = gtid; idx < 65536; idx += NWG*TPB) sysst(hT2 + idx, 0.f);  // zero buf0
  gbarL();
  lstm_enc(tid, cg, bg, 32, XPh, WhhPH, p.hlen, hT2, h_tT, nullptr, lds);
  gbarH();  // flush h_sT/h_s2/h_tT for S4/S5 normal reads

  // ---------------- S4: Ws_hs, htWt, htmW ----------------
  for (int task = gwave; task < 3584; task += NWG*8){
    const float* src; const float* wT; const float* bias; float* outp;
    int rb, cb, cols;
    if (task < 1024){ rb = task;        cb = 0;            src = h_sT; wT = WsT;    bias = nullptr; outp = Ws_hs; cols = 512; }
    else if (task < 1536){ rb = task-1024; cb = 0;         src = h_tT; wT = WtT;    bias = nullptr; outp = htWt;  cols = 512; }
    else { int t2 = task - 1536; cb = t2 >> 9; rb = t2 & 511; src = h_tT; wT = mWihRT; bias = bpM;  outp = htmW;  cols = 2048; }
    const int r0 = rb * 8;
    const int j0 = cb * 512 + lane * 8;
    const float* xr[8];
    #pragma unroll
    for (int r = 0; r < 8; ++r){
      int row = r0 + r;
      xr[r] = src + (size_t)(row >> 7) * 65536 + (row & 127);  // [t][k][b]
    }
    f8v bias8 = {0,0,0,0,0,0,0,0};
    if (bias) bias8 = *(const f8v*)(bias + j0);
    float acc[8][8];
    #pragma unroll
    for (int r = 0; r < 8; ++r){
      #pragma unroll
      for (int i = 0; i < 8; ++i) acc[r][i] = 0.f;
    }
    for (int k = 0; k < 512; ++k){
      f8v w8 = *(const f8v*)(wT + (size_t)k * cols + j0);
      #pragma unroll
      for (int r = 0; r < 8; ++r){
        float xv = xr[r][(size_t)k * 128];
        #pragma unroll
        for (int i = 0; i < 8; ++i) acc[r][i] += xv * w8[i];
      }
    }
    #pragma unroll
    for (int r = 0; r < 8; ++r){
      f8v o8;
      #pragma unroll
      for (int i = 0; i < 8; ++i) o8[i] = acc[r][i] + bias8[i];
      *(f8v*)(outp + (size_t)(r0 + r) * (size_t)cols + j0) = o8;
    }
  }
  gbarH();

  // ---------------- S5: match-LSTM loop ----------------
  const int b8 = tid & 7, hc32 = (tid >> 3) & 31, gp = tid >> 8;
  const int mb_ = bg*8 + b8, mhc = cg*32 + hc32;
  const float* dwrow = DW + (size_t)(mhc*2 + gp) * 2048;   // [1024][2]
  const int hyplen_b = p.hlen[mb_];
  const int sb = tid >> 6, sk = (tid & 63) * 8;
  float* stage  = lds;             // A: [8][516]; D: [8][1028]
  float* xchA   = lds + 8*516;     // [256]
  float* stage2 = lds;
  float* xch2   = lds + 8*1028;    // [256][2]
  float cm_reg = 0.f, hl_reg = 0.f;

  for (int k = 0; k < 32; ++k){
    const float* hmin  = hmT2 + (size_t)(k & 1) * 65536;
    float*       hmout = hmT2 + (size_t)((k + 1) & 1) * 65536;

    // --- A: q = htWt[k] + h_m @ Wm.T  (block: 32 cols x 8 b, 2-way k-split)
    {
      { // stage h_m slice
        const float* src = hmin + (size_t)(bg*8 + sb)*512 + sk;
        float2 v0 = sysld2(src), v1 = sysld2(src+2), v2 = sysld2(src+4), v3 = sysld2(src+6);
        float* dst = stage + sb*516 + sk;
        dst[0]=v0.x; dst[1]=v0.y; dst[2]=v1.x; dst[3]=v1.y;
        dst[4]=v2.x; dst[5]=v2.y; dst[6]=v3.x; dst[7]=v3.y;
      }
      __syncthreads();
      const int c32 = (tid >> 3) & 31, half = tid >> 8;
      const int c = cg*32 + c32;
      float a = 0.f;
      const float* hr = stage + b8*516 + half*256;
      const float* wr = p.Wm + (size_t)c*512 + half*256;
      #pragma unroll 2
      for (int kk = 0; kk < 256; kk += 4){
        float4 h4 = *(const float4*)(hr + kk);
        float4 w4 = *(const float4*)(wr + kk);
        a += h4.x*w4.x + h4.y*w4.y + h4.z*w4.z + h4.w*w4.w;
      }
      if (half == 1) xchA[c32*8 + b8] = a;
      __syncthreads();
      if (half == 0){
        float v = a + xchA[c32*8 + b8] + htWt[((size_t)k*128 + mb_)*512 + c];
        sysst(qbuf + (size_t)mb_*512 + c, v);
      }
    }
    gbarL();

    // --- BC: scores + softmax + a_k (block bb<128 owns one batch element)
    if (wg < 128){
      const int bb = wg;
      const float* qb = qbuf + (size_t)bb*512 + lane*8;
      float2 qa = sysld2(qb), qbv = sysld2(qb+2), qc = sysld2(qb+4), qd = sysld2(qb+6);
      float4 q0 = {qa.x, qa.y, qbv.x, qbv.y};
      float4 q1 = {qc.x, qc.y, qd.x, qd.y};
      float4 e0 = *(const float4*)(p.we + lane*8);
      float4 e1 = *(const float4*)(p.we + lane*8 + 4);
      #pragma unroll
      for (int si = 0; si < 8; ++si){
        int s = wave*8 + si;
        const float* wsr = Ws_hs + ((size_t)s*128 + bb)*512 + lane*8;  // L2-warm
        float4 s0 = *(const float4*)wsr;
        float4 s1 = *(const float4*)(wsr + 4);
        float v = tanhf_(s0.x + q0.x)*e0.x + tanhf_(s0.y + q0.y)*e0.y
                + tanhf_(s0.z + q0.z)*e0.z + tanhf_(s0.w + q0.w)*e0.w
                + tanhf_(s1.x + q1.x)*e1.x + tanhf_(s1.y + q1.y)*e1.y
                + tanhf_(s1.z + q1.z)*e1.z + tanhf_(s1.w + q1.w)*e1.w;
        v = wsum(v);
        if (lane == 0) lds[s] = v;
      }
      __syncthreads();
      if (wave == 0){
        float v = lds[lane];
        float m = wmaxr(v);
        float ex = __expf(v - m);
        float sm = wsum(ex);
        lds[64 + lane] = ex / sm;
      }
      __syncthreads();
      {
        float acc = 0.f;
        const float* hsb = h_s2 + (size_t)bb*512 + tid;   // L2-warm
        #pragma unroll 4
        for (int s = 0; s < 64; s += 4){
          float4 al = *(const float4*)(lds + 64 + s);
          acc += al.x * hsb[(size_t)(s+0)*65536]
               + al.y * hsb[(size_t)(s+1)*65536]
               + al.z * hsb[(size_t)(s+2)*65536]
               + al.w * hsb[(size_t)(s+3)*65536];
        }
        sysst(ak2 + (size_t)bb*512 + tid, acc);
      }
    }
    gbarL();

    // --- D: gates = htmW[k] + [a_k | h_m] @ DW ; cell update
    {
      { // stage [a_k | h_m] slice (32KB)
        const int sb2 = tid >> 6, c0 = (tid & 63) * 16;
        const float* src = (c0 < 512) ? (ak2 + (size_t)(bg*8 + sb2)*512 + c0)
                                      : (hmin + (size_t)(bg*8 + sb2)*512 + (c0 - 512));
        float* dst = stage2 + sb2*1028 + c0;
        #pragma unroll
        for (int i = 0; i < 16; i += 2){ float2 v = sysld2(src + i); dst[i] = v.x; dst[i+1] = v.y; }
      }
      __syncthreads();
      float a0 = 0.f, a1 = 0.f;
      const float* hr = stage2 + b8*1028;
      #pragma unroll 2
      for (int kk = 0; kk < 1024; kk += 4){
        float4 h4 = *(const float4*)(hr + kk);
        float4 wA = *(const float4*)(dwrow + kk*2);
        float4 wB = *(const float4*)(dwrow + kk*2 + 4);
        a0 += h4.x*wA.x + h4.y*wA.z + h4.z*wB.x + h4.w*wB.z;
        a1 += h4.x*wA.y + h4.y*wA.w + h4.z*wB.y + h4.w*wB.w;
      }
      float2 xg = *(const float2*)(htmW + ((size_t)k*128 + mb_)*2048 + mhc*4 + gp*2);
      a0 += xg.x; a1 += xg.y;
      if (gp == 1){ xch2[(b8*32+hc32)*2+0] = a0; xch2[(b8*32+hc32)*2+1] = a1; }
      __syncthreads();
      if (gp == 0){
        float gg = xch2[(b8*32+hc32)*2+0], go = xch2[(b8*32+hc32)*2+1];
        float iv = sigf(a0), fv = sigf(a1), gv = tanhf_(gg), ov = sigf(go);
        cm_reg = fv * cm_reg + iv * gv;
        float hv = ov * tanhf_(cm_reg);
        sysst(hmout + (size_t)mb_*512 + mhc, hv);
        if (k + 1 == hyplen_b) hl_reg = hv;
      }
    }
    gbarL();
  }

  if (gp == 0) hlast[(size_t)mb_*512 + mhc] = hl_reg;
  gbarH();

  // ---------------- S6: fc on block 0 ----------------
  if (wg == 0){
    for (int o = wave; o < 384; o += 8){
      int bb = o / 3, cls = o - bb*3;
      const float* hr = hlast + (size_t)bb*512 + lane*8;
      const float* wr = p.fcW + (size_t)cls*512 + lane*8;
      float4 h0 = *(const float4*)hr, h1 = *(const float4*)(hr + 4);
      float4 w0 = *(const float4*)wr, w1 = *(const float4*)(wr + 4);
      float v = h0.x*w0.x + h0.y*w0.y + h0.z*w0.z + h0.w*w0.w
              + h1.x*w1.x + h1.y*w1.y + h1.z*w1.z + h1.w*w1.w;
      v = wsum(v);
      if (lane == 0) p.out[o] = v + p.fcb[cls];
    }
  }
}

extern "C" void kernel_launch(void* const* d_in, const int* in_sizes, int n_in,
                              void* d_out, int out_size, void* d_ws, size_t ws_size,
                              hipStream_t stream) {
  if (ws_size < WS_FLOATS * sizeof(float)) return;  // fail clean, not OOB
  Params prm;
  prm.premise = (const int*)d_in[0];
  prm.plen    = (const int*)d_in[1];
  prm.hyp     = (const int*)d_in[2];
  prm.hlen    = (const int*)d_in[3];
  prm.embed   = (const float*)d_in[4];
  prm.pWih    = (const float*)d_in[5];
  prm.pWhh    = (const float*)d_in[6];
  prm.pb      = (const float*)d_in[7];
  prm.hWih    = (const float*)d_in[8];
  prm.hWhh    = (const float*)d_in[9];
  prm.hb      = (const float*)d_in[10];
  prm.mWih    = (const float*)d_in[11];
  prm.mWhh    = (const float*)d_in[12];
  prm.mb      = (const float*)d_in[13];
  prm.we      = (const float*)d_in[14];
  prm.Ws      = (const float*)d_in[15];
  prm.Wt      = (const float*)d_in[16];
  prm.Wm      = (const float*)d_in[17];
  prm.fcW     = (const float*)d_in[18];
  prm.fcb     = (const float*)d_in[19];
  prm.out     = (float*)d_out;
  prm.ws      = (float*)d_ws;
  mlstm<<<dim3(NWG), dim3(TPB), 0, stream>>>(prm);
}

// Round 3
// 4635.316 us; speedup vs baseline: 2.9259x; 1.2783x over previous
//
#include <hip/hip_runtime.h>

// MatchLSTM persistent-kernel, fp32, round 3.
// Change vs R2: the ~193 in-loop grid barriers no longer use a contended
// fetch_add counter (256 serialized RMWs ~= 20us/barrier). New gather barrier:
// per-block 64B-padded arrival slots (plain relaxed system stores), block 0
// polls all slots with 256 parallel lanes, release epoch replicated across 16
// cache lines. Monotonic epochs persist across graph replays via g_base.
// Heavy (L2 flush+inv) barriers at the 5 phase boundaries keep the R2 scheme.

#define NWG 256
#define TPB 512

typedef float f8v __attribute__((ext_vector_type(8)));

// ---- workspace layout (float offsets) ----
#define O_XPP      0ull          // [64][128][2048] premise input proj (+bias)
#define O_HTMW     0ull          // overlay after encoders: [32][128][2048]
#define O_HTWT     8388608ull    // [32][128][512]
#define O_WSHS     10485760ull   // [64][128][512]
#define O_XPH      16777216ull   // [32][128][2048]
#define O_HST      25165824ull   // [64][512][128]  masked premise h (k-major)
#define O_HS2      29360128ull   // [64][128][512]  masked premise h (h-major)
#define O_HTT      33554432ull   // [32][512][128]  masked hyp h (k-major)
#define O_WIHTP    35651584ull   // [300][2048] perm
#define O_WIHTH    36265984ull
#define O_WHHPP    36880384ull   // [1024 pair-rows][512 k][2] premise Whh
#define O_WHHPH    37928960ull
#define O_DW       38977536ull   // [1024 pair-rows][1024 k][2] match (mWihL | mWhh)
#define O_WST      41074688ull   // [512][512] k-major
#define O_WTT      41336832ull
#define O_MWIHRT   41598976ull   // [512][2048] perm
#define O_BPP      42647552ull   // [2048] perm biases
#define O_BPH      42649600ull
#define O_BPM      42651648ull
#define O_HT2      42653696ull   // [2][128][512] encoder h double buffer (coherent)
#define O_HMT2     42784768ull   // [2][128][512] match h double buffer (coherent)
#define O_QBUF     42915840ull   // [128][512] (coherent)
#define O_AK2      42981376ull   // [128][512] (coherent)
#define O_HLAST    43046912ull   // [128][512]
#define WS_FLOATS  43112448ull

__device__ unsigned g_cnt = 0u;          // heavy-barrier counter (monotonic)
__device__ unsigned g_gen = 0u;          // heavy-barrier generation
__device__ unsigned g_arr[NWG * 16];     // light-barrier arrival slots, 64B apart
__device__ unsigned g_relA[16 * 16];     // light-barrier release, 16 line copies
__device__ unsigned g_base = 0u;         // light-barrier epoch base across launches

struct Params {
  const int* premise; const int* plen; const int* hyp; const int* hlen;
  const float* embed;
  const float* pWih; const float* pWhh; const float* pb;
  const float* hWih; const float* hWhh; const float* hb;
  const float* mWih; const float* mWhh; const float* mb;
  const float* we; const float* Ws; const float* Wt; const float* Wm;
  const float* fcW; const float* fcb;
  float* out; float* ws;
};

// ---- coherent (system-scope, L2-bypassing) accessors for mutable state ----
__device__ __forceinline__ float2 sysld2(const float* p){
  unsigned long long u = __hip_atomic_load((const unsigned long long*)p,
      __ATOMIC_RELAXED, __HIP_MEMORY_SCOPE_SYSTEM);
  union { unsigned long long u; float2 f; } c; c.u = u; return c.f;
}
__device__ __forceinline__ void sysst(float* p, float v){
  union { float f; unsigned u; } c; c.f = v;
  __hip_atomic_store((unsigned*)p, c.u, __ATOMIC_RELAXED, __HIP_MEMORY_SCOPE_SYSTEM);
}

// Heavy barrier (phase boundaries only): flush + invalidate L2 so normal
// loads/stores become grid-visible. Proven correct in R1/R2.
__device__ __forceinline__ void gbarH(){
  __syncthreads();
  if (threadIdx.x == 0){
    __threadfence();
    unsigned snap = __hip_atomic_load(&g_gen, __ATOMIC_RELAXED, __HIP_MEMORY_SCOPE_AGENT);
    unsigned n = __hip_atomic_fetch_add(&g_cnt, 1u, __ATOMIC_ACQ_REL, __HIP_MEMORY_SCOPE_AGENT);
    if ((n & 255u) == 255u){
      __hip_atomic_store(&g_gen, snap + 1u, __ATOMIC_RELEASE, __HIP_MEMORY_SCOPE_AGENT);
    } else {
      unsigned g;
      do {
        __builtin_amdgcn_s_sleep(2);
        g = __hip_atomic_load(&g_gen, __ATOMIC_ACQUIRE, __HIP_MEMORY_SCOPE_AGENT);
      } while ((int)(g - snap) <= 0);
    }
  }
  __syncthreads();
}

// Light barrier: contention-free gather. No RMW, no cache maintenance.
// Visibility: __syncthreads drains vmcnt, so all prior system-scope stores are
// at the coherence point before the arrival store issues (R2-validated).
__device__ __forceinline__ void gbarL(unsigned e, int wg, int tid){
  __syncthreads();
  if (wg == 0){
    if (tid == 0)
      __hip_atomic_store(&g_arr[0], e, __ATOMIC_RELAXED, __HIP_MEMORY_SCOPE_SYSTEM);
    if (tid < NWG){
      while ((int)(__hip_atomic_load(&g_arr[tid*16], __ATOMIC_RELAXED,
                                     __HIP_MEMORY_SCOPE_SYSTEM) - e) < 0)
        __builtin_amdgcn_s_sleep(1);
    }
    __syncthreads();
    if (tid < 16)
      __hip_atomic_store(&g_relA[tid*16], e, __ATOMIC_RELAXED, __HIP_MEMORY_SCOPE_SYSTEM);
  } else {
    if (tid == 0){
      __hip_atomic_store(&g_arr[wg*16], e, __ATOMIC_RELAXED, __HIP_MEMORY_SCOPE_SYSTEM);
      while ((int)(__hip_atomic_load(&g_relA[(wg & 15)*16], __ATOMIC_RELAXED,
                                     __HIP_MEMORY_SCOPE_SYSTEM) - e) < 0)
        __builtin_amdgcn_s_sleep(1);
    }
    __syncthreads();
  }
}

__device__ __forceinline__ float sigf(float x){ return 1.0f/(1.0f + __expf(-x)); }
__device__ __forceinline__ float tanhf_(float x){ return 2.0f/(1.0f + __expf(-2.0f*x)) - 1.0f; }

__device__ __forceinline__ float wsum(float v){
  #pragma unroll
  for (int o = 32; o > 0; o >>= 1) v += __shfl_xor(v, o, 64);
  return v;
}
__device__ __forceinline__ float wmaxr(float v){
  #pragma unroll
  for (int o = 32; o > 0; o >>= 1) v = fmaxf(v, __shfl_xor(v, o, 64));
  return v;
}

// One encoder LSTM. Block = (cg: 32 h-cols, bg: 8 batch). Thread (b8,hc32,gp)
// owns gates {gp*2, gp*2+1} of (b,hc); full K=512 dot from LDS-staged h.
__device__ void lstm_enc(int wg, int tid, int cg, int bg, int T,
    const float* __restrict__ XP, const float* __restrict__ WPair,
    const int* __restrict__ lens, float* hbuf,
    float* __restrict__ houtT, float* __restrict__ hout2, float* lds,
    unsigned& ep)
{
  const int b8 = tid & 7, hc32 = (tid >> 3) & 31, gp = tid >> 8;
  const int b = bg*8 + b8, hc = cg*32 + hc32;
  const float* wrow = WPair + (size_t)(hc*2 + gp) * 1024;   // [512][2]
  const int mylen = lens[b];
  const int sb = tid >> 6, sk = (tid & 63) * 8;
  float* stage = lds;            // [8][516] padded
  float* xch   = lds + 8*516;    // [256][2]
  float c_reg = 0.f;

  for (int t = 0; t < T; ++t){
    const float* hin  = hbuf + (size_t)(t & 1) * 65536;
    float*       hout = hbuf + (size_t)((t + 1) & 1) * 65536;
    { // cooperative coherent load of h[bg*8..+8][512] -> LDS (16KB)
      const float* src = hin + (size_t)(bg*8 + sb)*512 + sk;
      float2 v0 = sysld2(src), v1 = sysld2(src+2), v2 = sysld2(src+4), v3 = sysld2(src+6);
      float* dst = stage + sb*516 + sk;
      float4 w0 = {v0.x, v0.y, v1.x, v1.y};
      float4 w1 = {v2.x, v2.y, v3.x, v3.y};
      *(float4*)dst = w0; *(float4*)(dst+4) = w1;
    }
    __syncthreads();
    float a0 = 0.f, a1 = 0.f;
    const float* hr = stage + b8*516;
    #pragma unroll 2
    for (int k = 0; k < 512; k += 4){
      float4 h4 = *(const float4*)(hr + k);
      float4 wA = *(const float4*)(wrow + k*2);
      float4 wB = *(const float4*)(wrow + k*2 + 4);
      a0 += h4.x*wA.x + h4.y*wA.z + h4.z*wB.x + h4.w*wB.z;
      a1 += h4.x*wA.y + h4.y*wA.w + h4.z*wB.y + h4.w*wB.w;
    }
    float2 xg = *(const float2*)(XP + ((size_t)t*128 + b)*2048 + hc*4 + gp*2);
    a0 += xg.x; a1 += xg.y;
    if (gp == 1){ xch[(b8*32+hc32)*2+0] = a0; xch[(b8*32+hc32)*2+1] = a1; }
    __syncthreads();
    if (gp == 0){
      float gg = xch[(b8*32+hc32)*2+0], go = xch[(b8*32+hc32)*2+1];
      float iv = sigf(a0), fv = sigf(a1), gv = tanhf_(gg), ov = sigf(go);
      c_reg = fv * c_reg + iv * gv;
      float hv = ov * tanhf_(c_reg);
      sysst(hout + (size_t)b*512 + hc, hv);          // coherent recurrence state
      float hm = (t < mylen) ? hv : 0.f;             // masked outputs (normal)
      houtT[((size_t)t*512 + hc)*128 + b] = hm;
      if (hout2) hout2[((size_t)t*128 + b)*512 + hc] = hm;
    }
    ++ep; gbarL(ep, wg, tid);
  }
}

__global__ __launch_bounds__(TPB, 2) void mlstm(Params p){
  const int wg = blockIdx.x, tid = threadIdx.x;
  const int lane = tid & 63, wave = tid >> 6;
  const int gtid = wg * TPB + tid;
  const int gwave = wg * 8 + wave;
  const int cg = wg & 15, bg = wg >> 4;   // col-group / batch-group roles
  __shared__ float lds[8736];             // D: [8][1028] + xch 512
  __shared__ unsigned sh_base;

  if (tid == 0)
    sh_base = __hip_atomic_load(&g_base, __ATOMIC_RELAXED, __HIP_MEMORY_SCOPE_SYSTEM);
  __syncthreads();
  unsigned ep = sh_base;

  float* const ws     = p.ws;
  float* const XPp    = ws + O_XPP;
  float* const XPh    = ws + O_XPH;
  float* const htmW   = ws + O_HTMW;
  float* const htWt   = ws + O_HTWT;
  float* const Ws_hs  = ws + O_WSHS;
  float* const h_sT   = ws + O_HST;
  float* const h_s2   = ws + O_HS2;
  float* const h_tT   = ws + O_HTT;
  float* const WihTp  = ws + O_WIHTP;
  float* const WihTh  = ws + O_WIHTH;
  float* const WhhPP  = ws + O_WHHPP;
  float* const WhhPH  = ws + O_WHHPH;
  float* const DW     = ws + O_DW;
  float* const WsT    = ws + O_WST;
  float* const WtT    = ws + O_WTT;
  float* const mWihRT = ws + O_MWIHRT;
  float* const bpP    = ws + O_BPP;
  float* const bpH    = ws + O_BPH;
  float* const bpM    = ws + O_BPM;
  float* const hT2    = ws + O_HT2;
  float* const hmT2   = ws + O_HMT2;
  float* const qbuf   = ws + O_QBUF;
  float* const ak2    = ws + O_AK2;
  float* const hlast  = ws + O_HLAST;

  // ---------------- S0: weight layout transforms ----------------
  for (int idx = gtid; idx < 300*2048; idx += NWG*TPB){
    int e = idx >> 11, jp = idx & 2047;
    int oc = (jp & 3) * 512 + (jp >> 2);
    WihTp[idx] = p.pWih[(size_t)oc*300 + e];
    WihTh[idx] = p.hWih[(size_t)oc*300 + e];
  }
  for (int idx = gtid; idx < 1024*512*2; idx += NWG*TPB){
    int g = idx & 1, k = (idx >> 1) & 511, pp = idx >> 10;
    int hc = pp >> 1, gp = pp & 1, oc = (gp*2+g)*512 + hc;
    WhhPP[idx] = p.pWhh[(size_t)oc*512 + k];
    WhhPH[idx] = p.hWhh[(size_t)oc*512 + k];
  }
  for (int idx = gtid; idx < 1024*1024*2; idx += NWG*TPB){
    int g = idx & 1, k = (idx >> 1) & 1023, pp = idx >> 11;
    int hc = pp >> 1, gp = pp & 1, oc = (gp*2+g)*512 + hc;
    DW[idx] = (k < 512) ? p.mWih[(size_t)oc*1024 + k]
                        : p.mWhh[(size_t)oc*512 + (k - 512)];
  }
  for (int idx = gtid; idx < 512*512; idx += NWG*TPB){
    int k = idx >> 9, h = idx & 511;
    WsT[idx] = p.Ws[(size_t)h*512 + k];
    WtT[idx] = p.Wt[(size_t)h*512 + k];
  }
  for (int idx = gtid; idx < 512*2048; idx += NWG*TPB){
    int k = idx >> 11, jp = idx & 2047;
    int oc = (jp & 3) * 512 + (jp >> 2);
    mWihRT[idx] = p.mWih[(size_t)oc*1024 + 512 + k];
  }
  for (int idx = gtid; idx < 2048; idx += NWG*TPB){
    int oc = (idx & 3) * 512 + (idx >> 2);
    bpP[idx] = p.pb[oc]; bpH[idx] = p.hb[oc]; bpM[idx] = p.mb[oc];
  }
  for (int idx = gtid; idx < 131072; idx += NWG*TPB){ hT2[idx] = 0.f; hmT2[idx] = 0.f; }
  gbarH();

  // ---------------- S1: XP = embed[tokens] @ WihT + bias ----------------
  for (int task = gwave; task < 6144; task += NWG*8){
    const bool prem = task < 4096;
    int rb, cb;
    if (prem){ cb = task >> 10; rb = task & 1023; }
    else { int t2 = task - 4096; cb = t2 >> 9; rb = t2 & 511; }
    const int r0 = rb * 8;
    const int* toks = prem ? p.premise : p.hyp;
    const float* wT = prem ? WihTp : WihTh;
    const float* bias = prem ? bpP : bpH;
    float* outp = prem ? XPp : XPh;
    const int j0 = cb * 512 + lane * 8;
    const float* xr[8];
    #pragma unroll
    for (int r = 0; r < 8; ++r) xr[r] = p.embed + (size_t)toks[r0 + r] * 300;
    f8v bias8 = *(const f8v*)(bias + j0);
    float acc[8][8];
    #pragma unroll
    for (int r = 0; r < 8; ++r){
      #pragma unroll
      for (int i = 0; i < 8; ++i) acc[r][i] = 0.f;
    }
    for (int e = 0; e < 300; ++e){
      f8v w8 = *(const f8v*)(wT + (size_t)e * 2048 + j0);
      #pragma unroll
      for (int r = 0; r < 8; ++r){
        float xv = xr[r][e];
        #pragma unroll
        for (int i = 0; i < 8; ++i) acc[r][i] += xv * w8[i];
      }
    }
    #pragma unroll
    for (int r = 0; r < 8; ++r){
      f8v o8;
      #pragma unroll
      for (int i = 0; i < 8; ++i) o8[i] = acc[r][i] + bias8[i];
      *(f8v*)(outp + (size_t)(r0 + r) * 2048 + j0) = o8;
    }
  }
  gbarH();

  // ---------------- S2/S3: encoder LSTMs ----------------
  lstm_enc(wg, tid, cg, bg, 64, XPp, WhhPP, p.plen, hT2, h_sT, h_s2, lds, ep);
  for (int idx = gtid; idx < 65536; idx += NWG*TPB) sysst(hT2 + idx, 0.f);  // zero buf0
  ++ep; gbarL(ep, wg, tid);
  lstm_enc(wg, tid, cg, bg, 32, XPh, WhhPH, p.hlen, hT2, h_tT, nullptr, lds, ep);
  gbarH();  // flush h_sT/h_s2/h_tT for S4/S5 normal reads

  // ---------------- S4: Ws_hs, htWt, htmW ----------------
  for (int task = gwave; task < 3584; task += NWG*8){
    const float* src; const float* wT; const float* bias; float* outp;
    int rb, cb, cols;
    if (task < 1024){ rb = task;        cb = 0;            src = h_sT; wT = WsT;    bias = nullptr; outp = Ws_hs; cols = 512; }
    else if (task < 1536){ rb = task-1024; cb = 0;         src = h_tT; wT = WtT;    bias = nullptr; outp = htWt;  cols = 512; }
    else { int t2 = task - 1536; cb = t2 >> 9; rb = t2 & 511; src = h_tT; wT = mWihRT; bias = bpM;  outp = htmW;  cols = 2048; }
    const int r0 = rb * 8;
    const int j0 = cb * 512 + lane * 8;
    const float* xr[8];
    #pragma unroll
    for (int r = 0; r < 8; ++r){
      int row = r0 + r;
      xr[r] = src + (size_t)(row >> 7) * 65536 + (row & 127);  // [t][k][b]
    }
    f8v bias8 = {0,0,0,0,0,0,0,0};
    if (bias) bias8 = *(const f8v*)(bias + j0);
    float acc[8][8];
    #pragma unroll
    for (int r = 0; r < 8; ++r){
      #pragma unroll
      for (int i = 0; i < 8; ++i) acc[r][i] = 0.f;
    }
    for (int k = 0; k < 512; ++k){
      f8v w8 = *(const f8v*)(wT + (size_t)k * cols + j0);
      #pragma unroll
      for (int r = 0; r < 8; ++r){
        float xv = xr[r][(size_t)k * 128];
        #pragma unroll
        for (int i = 0; i < 8; ++i) acc[r][i] += xv * w8[i];
      }
    }
    #pragma unroll
    for (int r = 0; r < 8; ++r){
      f8v o8;
      #pragma unroll
      for (int i = 0; i < 8; ++i) o8[i] = acc[r][i] + bias8[i];
      *(f8v*)(outp + (size_t)(r0 + r) * (size_t)cols + j0) = o8;
    }
  }
  gbarH();

  // ---------------- S5: match-LSTM loop ----------------
  const int b8 = tid & 7, hc32 = (tid >> 3) & 31, gp = tid >> 8;
  const int mb_ = bg*8 + b8, mhc = cg*32 + hc32;
  const float* dwrow = DW + (size_t)(mhc*2 + gp) * 2048;   // [1024][2]
  const int hyplen_b = p.hlen[mb_];
  const int sb = tid >> 6, sk = (tid & 63) * 8;
  float* stage  = lds;             // A: [8][516]; D: [8][1028]
  float* xchA   = lds + 8*516;     // [256]
  float* stage2 = lds;
  float* xch2   = lds + 8*1028;    // [256][2]
  float cm_reg = 0.f, hl_reg = 0.f;

  for (int k = 0; k < 32; ++k){
    const float* hmin  = hmT2 + (size_t)(k & 1) * 65536;
    float*       hmout = hmT2 + (size_t)((k + 1) & 1) * 65536;

    // --- A: q = htWt[k] + h_m @ Wm.T  (block: 32 cols x 8 b, 2-way k-split)
    {
      { // stage h_m slice
        const float* src = hmin + (size_t)(bg*8 + sb)*512 + sk;
        float2 v0 = sysld2(src), v1 = sysld2(src+2), v2 = sysld2(src+4), v3 = sysld2(src+6);
        float* dst = stage + sb*516 + sk;
        float4 w0 = {v0.x, v0.y, v1.x, v1.y};
        float4 w1 = {v2.x, v2.y, v3.x, v3.y};
        *(float4*)dst = w0; *(float4*)(dst+4) = w1;
      }
      __syncthreads();
      const int c32 = (tid >> 3) & 31, half = tid >> 8;
      const int c = cg*32 + c32;
      float a = 0.f;
      const float* hr = stage + b8*516 + half*256;
      const float* wr = p.Wm + (size_t)c*512 + half*256;
      #pragma unroll 2
      for (int kk = 0; kk < 256; kk += 4){
        float4 h4 = *(const float4*)(hr + kk);
        float4 w4 = *(const float4*)(wr + kk);
        a += h4.x*w4.x + h4.y*w4.y + h4.z*w4.z + h4.w*w4.w;
      }
      if (half == 1) xchA[c32*8 + b8] = a;
      __syncthreads();
      if (half == 0){
        float v = a + xchA[c32*8 + b8] + htWt[((size_t)k*128 + mb_)*512 + c];
        sysst(qbuf + (size_t)mb_*512 + c, v);
      }
    }
    ++ep; gbarL(ep, wg, tid);

    // --- BC: scores + softmax + a_k (block bb<128 owns one batch element)
    if (wg < 128){
      const int bb = wg;
      const float* qb = qbuf + (size_t)bb*512 + lane*8;
      float2 qa = sysld2(qb), qbv = sysld2(qb+2), qc = sysld2(qb+4), qd = sysld2(qb+6);
      float4 q0 = {qa.x, qa.y, qbv.x, qbv.y};
      float4 q1 = {qc.x, qc.y, qd.x, qd.y};
      float4 e0 = *(const float4*)(p.we + lane*8);
      float4 e1 = *(const float4*)(p.we + lane*8 + 4);
      #pragma unroll
      for (int si = 0; si < 8; ++si){
        int s = wave*8 + si;
        const float* wsr = Ws_hs + ((size_t)s*128 + bb)*512 + lane*8;  // L2-warm
        float4 s0 = *(const float4*)wsr;
        float4 s1 = *(const float4*)(wsr + 4);
        float v = tanhf_(s0.x + q0.x)*e0.x + tanhf_(s0.y + q0.y)*e0.y
                + tanhf_(s0.z + q0.z)*e0.z + tanhf_(s0.w + q0.w)*e0.w
                + tanhf_(s1.x + q1.x)*e1.x + tanhf_(s1.y + q1.y)*e1.y
                + tanhf_(s1.z + q1.z)*e1.z + tanhf_(s1.w + q1.w)*e1.w;
        v = wsum(v);
        if (lane == 0) lds[s] = v;
      }
      __syncthreads();
      if (wave == 0){
        float v = lds[lane];
        float m = wmaxr(v);
        float ex = __expf(v - m);
        float sm = wsum(ex);
        lds[64 + lane] = ex / sm;
      }
      __syncthreads();
      {
        float acc = 0.f;
        const float* hsb = h_s2 + (size_t)bb*512 + tid;   // L2-warm
        #pragma unroll 4
        for (int s = 0; s < 64; s += 4){
          float4 al = *(const float4*)(lds + 64 + s);
          acc += al.x * hsb[(size_t)(s+0)*65536]
               + al.y * hsb[(size_t)(s+1)*65536]
               + al.z * hsb[(size_t)(s+2)*65536]
               + al.w * hsb[(size_t)(s+3)*65536];
        }
        sysst(ak2 + (size_t)bb*512 + tid, acc);
      }
    }
    ++ep; gbarL(ep, wg, tid);

    // --- D: gates = htmW[k] + [a_k | h_m] @ DW ; cell update
    {
      { // stage [a_k | h_m] slice (32KB)
        const int sb2 = tid >> 6, c0 = (tid & 63) * 16;
        const float* src = (c0 < 512) ? (ak2 + (size_t)(bg*8 + sb2)*512 + c0)
                                      : (hmin + (size_t)(bg*8 + sb2)*512 + (c0 - 512));
        float* dst = stage2 + sb2*1028 + c0;
        #pragma unroll
        for (int i = 0; i < 16; i += 4){
          float2 va = sysld2(src + i), vb = sysld2(src + i + 2);
          float4 w = {va.x, va.y, vb.x, vb.y};
          *(float4*)(dst + i) = w;
        }
      }
      __syncthreads();
      float a0 = 0.f, a1 = 0.f;
      const float* hr = stage2 + b8*1028;
      #pragma unroll 2
      for (int kk = 0; kk < 1024; kk += 4){
        float4 h4 = *(const float4*)(hr + kk);
        float4 wA = *(const float4*)(dwrow + kk*2);
        float4 wB = *(const float4*)(dwrow + kk*2 + 4);
        a0 += h4.x*wA.x + h4.y*wA.z + h4.z*wB.x + h4.w*wB.z;
        a1 += h4.x*wA.y + h4.y*wA.w + h4.z*wB.y + h4.w*wB.w;
      }
      float2 xg = *(const float2*)(htmW + ((size_t)k*128 + mb_)*2048 + mhc*4 + gp*2);
      a0 += xg.x; a1 += xg.y;
      if (gp == 1){ xch2[(b8*32+hc32)*2+0] = a0; xch2[(b8*32+hc32)*2+1] = a1; }
      __syncthreads();
      if (gp == 0){
        float gg = xch2[(b8*32+hc32)*2+0], go = xch2[(b8*32+hc32)*2+1];
        float iv = sigf(a0), fv = sigf(a1), gv = tanhf_(gg), ov = sigf(go);
        cm_reg = fv * cm_reg + iv * gv;
        float hv = ov * tanhf_(cm_reg);
        sysst(hmout + (size_t)mb_*512 + mhc, hv);
        if (k + 1 == hyplen_b) hl_reg = hv;
      }
    }
    ++ep; gbarL(ep, wg, tid);
  }

  if (gp == 0) hlast[(size_t)mb_*512 + mhc] = hl_reg;
  gbarH();

  // Persist epoch base for the next launch (graph replays) — block 0 only,
  // after the last barrier. Device globals are never re-poisoned.
  if (wg == 0 && tid == 0)
    __hip_atomic_store(&g_base, ep, __ATOMIC_RELAXED, __HIP_MEMORY_SCOPE_SYSTEM);

  // ---------------- S6: fc on block 0 ----------------
  if (wg == 0){
    for (int o = wave; o < 384; o += 8){
      int bb = o / 3, cls = o - bb*3;
      const float* hr = hlast + (size_t)bb*512 + lane*8;
      const float* wr = p.fcW + (size_t)cls*512 + lane*8;
      float4 h0 = *(const float4*)hr, h1 = *(const float4*)(hr + 4);
      float4 w0 = *(const float4*)wr, w1 = *(const float4*)(wr + 4);
      float v = h0.x*w0.x + h0.y*w0.y + h0.z*w0.z + h0.w*w0.w
              + h1.x*w1.x + h1.y*w1.y + h1.z*w1.z + h1.w*w1.w;
      v = wsum(v);
      if (lane == 0) p.out[o] = v + p.fcb[cls];
    }
  }
}

extern "C" void kernel_launch(void* const* d_in, const int* in_sizes, int n_in,
                              void* d_out, int out_size, void* d_ws, size_t ws_size,
                              hipStream_t stream) {
  if (ws_size < WS_FLOATS * sizeof(float)) return;  // fail clean, not OOB
  Params prm;
  prm.premise = (const int*)d_in[0];
  prm.plen    = (const int*)d_in[1];
  prm.hyp     = (const int*)d_in[2];
  prm.hlen    = (const int*)d_in[3];
  prm.embed   = (const float*)d_in[4];
  prm.pWih    = (const float*)d_in[5];
  prm.pWhh    = (const float*)d_in[6];
  prm.pb      = (const float*)d_in[7];
  prm.hWih    = (const float*)d_in[8];
  prm.hWhh    = (const float*)d_in[9];
  prm.hb      = (const float*)d_in[10];
  prm.mWih    = (const float*)d_in[11];
  prm.mWhh    = (const float*)d_in[12];
  prm.mb      = (const float*)d_in[13];
  prm.we      = (const float*)d_in[14];
  prm.Ws      = (const float*)d_in[15];
  prm.Wt      = (const float*)d_in[16];
  prm.Wm      = (const float*)d_in[17];
  prm.fcW     = (const float*)d_in[18];
  prm.fcb     = (const float*)d_in[19];
  prm.out     = (float*)d_out;
  prm.ws      = (float*)d_ws;
  mlstm<<<dim3(NWG), dim3(TPB), 0, stream>>>(prm);
}

// Round 4
// 4465.150 us; speedup vs baseline: 3.0375x; 1.0381x over previous
//
#include <hip/hip_runtime.h>

// MatchLSTM persistent-kernel, fp32, round 4.
// Change vs R3: in-loop grid barriers replaced by producer->consumer epoch
// flags (per-block monotone counters, 64B-padded, relaxed system scope).
// Each consumer polls only its true producer set (<=16 blocks), one visibility
// hop, no global straggler coupling. t==0/k==0 steps treat prior state as
// zero (skip stage+dot), removing all state zero-init and one barrier.
// Heavy (L2 flush+inv) barriers remain at the 5 phase boundaries (validated).

#define NWG 256
#define TPB 512

typedef float f8v __attribute__((ext_vector_type(8)));

// ---- workspace layout (float offsets) ----
#define O_XPP      0ull          // [64][128][2048] premise input proj (+bias)
#define O_HTMW     0ull          // overlay after encoders: [32][128][2048]
#define O_HTWT     8388608ull    // [32][128][512]
#define O_WSHS     10485760ull   // [64][128][512]
#define O_XPH      16777216ull   // [32][128][2048]
#define O_HST      25165824ull   // [64][512][128]  masked premise h (k-major)
#define O_HS2      29360128ull   // [64][128][512]  masked premise h (h-major)
#define O_HTT      33554432ull   // [32][512][128]  masked hyp h (k-major)
#define O_WIHTP    35651584ull   // [300][2048] perm
#define O_WIHTH    36265984ull
#define O_WHHPP    36880384ull   // [1024 pair-rows][512 k][2] premise Whh
#define O_WHHPH    37928960ull
#define O_DW       38977536ull   // [1024 pair-rows][1024 k][2] match (mWihL | mWhh)
#define O_WST      41074688ull   // [512][512] k-major
#define O_WTT      41336832ull
#define O_MWIHRT   41598976ull   // [512][2048] perm
#define O_BPP      42647552ull   // [2048] perm biases
#define O_BPH      42649600ull
#define O_BPM      42651648ull
#define O_HT2      42653696ull   // [2][128][512] encoder h double buffer (coherent)
#define O_HMT2     42784768ull   // [2][128][512] match h double buffer (coherent)
#define O_QBUF     42915840ull   // [128][512] (coherent)
#define O_AK2      42981376ull   // [128][512] (coherent)
#define O_HLAST    43046912ull   // [128][512]
#define WS_FLOATS  43112448ull

__device__ unsigned g_cnt = 0u;          // heavy-barrier counter (monotonic)
__device__ unsigned g_gen = 0u;          // heavy-barrier generation
__device__ unsigned g_FE[NWG * 16];      // encoder step flags (64B padded)
__device__ unsigned g_FA[NWG * 16];      // match A flags
__device__ unsigned g_FB[NWG * 16];      // match BC flags
__device__ unsigned g_FD[NWG * 16];      // match D flags
__device__ unsigned g_base2 = 0u;        // flag epoch base across launches

struct Params {
  const int* premise; const int* plen; const int* hyp; const int* hlen;
  const float* embed;
  const float* pWih; const float* pWhh; const float* pb;
  const float* hWih; const float* hWhh; const float* hb;
  const float* mWih; const float* mWhh; const float* mb;
  const float* we; const float* Ws; const float* Wt; const float* Wm;
  const float* fcW; const float* fcb;
  float* out; float* ws;
};

// ---- coherent (system-scope, L2-bypassing) accessors for mutable state ----
__device__ __forceinline__ float2 sysld2(const float* p){
  unsigned long long u = __hip_atomic_load((const unsigned long long*)p,
      __ATOMIC_RELAXED, __HIP_MEMORY_SCOPE_SYSTEM);
  union { unsigned long long u; float2 f; } c; c.u = u; return c.f;
}
__device__ __forceinline__ void sysst(float* p, float v){
  union { float f; unsigned u; } c; c.f = v;
  __hip_atomic_store((unsigned*)p, c.u, __ATOMIC_RELAXED, __HIP_MEMORY_SCOPE_SYSTEM);
}
__device__ __forceinline__ void fbump(unsigned* a, unsigned v){
  __hip_atomic_store(a, v, __ATOMIC_RELAXED, __HIP_MEMORY_SCOPE_SYSTEM);
}
// Poll a producer flag until it reaches target (signed diff handles wrap).
__device__ __forceinline__ void waitflag(const unsigned* a, unsigned tgt){
  while ((int)(__hip_atomic_load(a, __ATOMIC_RELAXED,
               __HIP_MEMORY_SCOPE_SYSTEM) - tgt) < 0)
    __builtin_amdgcn_s_sleep(1);
}

// Heavy barrier (phase boundaries only): flush + invalidate L2 so normal
// loads/stores become grid-visible. Proven correct in R1-R3.
__device__ __forceinline__ void gbarH(){
  __syncthreads();
  if (threadIdx.x == 0){
    __threadfence();
    unsigned snap = __hip_atomic_load(&g_gen, __ATOMIC_RELAXED, __HIP_MEMORY_SCOPE_AGENT);
    unsigned n = __hip_atomic_fetch_add(&g_cnt, 1u, __ATOMIC_ACQ_REL, __HIP_MEMORY_SCOPE_AGENT);
    if ((n & 255u) == 255u){
      __hip_atomic_store(&g_gen, snap + 1u, __ATOMIC_RELEASE, __HIP_MEMORY_SCOPE_AGENT);
    } else {
      unsigned g;
      do {
        __builtin_amdgcn_s_sleep(2);
        g = __hip_atomic_load(&g_gen, __ATOMIC_ACQUIRE, __HIP_MEMORY_SCOPE_AGENT);
      } while ((int)(g - snap) <= 0);
    }
  }
  __syncthreads();
}

__device__ __forceinline__ float sigf(float x){ return 1.0f/(1.0f + __expf(-x)); }
__device__ __forceinline__ float tanhf_(float x){ return 2.0f/(1.0f + __expf(-2.0f*x)) - 1.0f; }

__device__ __forceinline__ float wsum(float v){
  #pragma unroll
  for (int o = 32; o > 0; o >>= 1) v += __shfl_xor(v, o, 64);
  return v;
}
__device__ __forceinline__ float wmaxr(float v){
  #pragma unroll
  for (int o = 32; o > 0; o >>= 1) v = fmaxf(v, __shfl_xor(v, o, 64));
  return v;
}

// One encoder LSTM. Block = (cg: 32 h-cols, bg: 8 batch). Thread (b8,hc32,gp)
// owns gates {gp*2, gp*2+1} of (b,hc); full K=512 dot from LDS-staged h.
// Sync: per-step flag wait on the 16 bg-peers; t==0 treats h as zero.
__device__ void lstm_enc(int wg, int tid, int lane, int cg, int bg, int T,
    const float* __restrict__ XP, const float* __restrict__ WPair,
    const int* __restrict__ lens, float* hbuf,
    float* __restrict__ houtT, float* __restrict__ hout2, float* lds,
    unsigned tb)
{
  const int b8 = tid & 7, hc32 = (tid >> 3) & 31, gp = tid >> 8;
  const int b = bg*8 + b8, hc = cg*32 + hc32;
  const float* wrow = WPair + (size_t)(hc*2 + gp) * 1024;   // [512][2]
  const int mylen = lens[b];
  const int sb = tid >> 6, sk = (tid & 63) * 8;
  float* stage = lds;            // [8][516] padded
  float* xch   = lds + 8*516;    // [256][2]
  float c_reg = 0.f;
  const unsigned* peer = &g_FE[(((unsigned)bg << 4) | (lane & 15)) * 16];

  for (int t = 0; t < T; ++t){
    const float* hin  = hbuf + (size_t)(t & 1) * 65536;
    float*       hout = hbuf + (size_t)((t + 1) & 1) * 65536;
    // every wave polls the 16 bg-peers (RAW on h(t-1), WAR on hout buffer)
    if (lane < 16) waitflag(peer, tb + t);
    if (t > 0){ // stage h(t-1)[bg rows] -> LDS (each wave stages its row)
      const float* src = hin + (size_t)(bg*8 + sb)*512 + sk;
      float2 v0 = sysld2(src), v1 = sysld2(src+2), v2 = sysld2(src+4), v3 = sysld2(src+6);
      float* dst = stage + sb*516 + sk;
      float4 w0 = {v0.x, v0.y, v1.x, v1.y};
      float4 w1 = {v2.x, v2.y, v3.x, v3.y};
      *(float4*)dst = w0; *(float4*)(dst+4) = w1;
    }
    __syncthreads();
    float a0 = 0.f, a1 = 0.f;
    if (t > 0){
      const float* hr = stage + b8*516;
      #pragma unroll 2
      for (int k = 0; k < 512; k += 4){
        float4 h4 = *(const float4*)(hr + k);
        float4 wA = *(const float4*)(wrow + k*2);
        float4 wB = *(const float4*)(wrow + k*2 + 4);
        a0 += h4.x*wA.x + h4.y*wA.z + h4.z*wB.x + h4.w*wB.z;
        a1 += h4.x*wA.y + h4.y*wA.w + h4.z*wB.y + h4.w*wB.w;
      }
    }
    float2 xg = *(const float2*)(XP + ((size_t)t*128 + b)*2048 + hc*4 + gp*2);
    a0 += xg.x; a1 += xg.y;
    if (gp == 1){ xch[(b8*32+hc32)*2+0] = a0; xch[(b8*32+hc32)*2+1] = a1; }
    __syncthreads();
    if (gp == 0){
      float gg = xch[(b8*32+hc32)*2+0], go = xch[(b8*32+hc32)*2+1];
      float iv = sigf(a0), fv = sigf(a1), gv = tanhf_(gg), ov = sigf(go);
      c_reg = fv * c_reg + iv * gv;
      float hv = ov * tanhf_(c_reg);
      sysst(hout + (size_t)b*512 + hc, hv);          // coherent recurrence state
      float hm = (t < mylen) ? hv : 0.f;             // masked outputs (normal)
      houtT[((size_t)t*512 + hc)*128 + b] = hm;
      if (hout2) hout2[((size_t)t*128 + b)*512 + hc] = hm;
    }
    __syncthreads();                                  // drains all waves' vmem
    if (tid == 0) fbump(&g_FE[wg*16], tb + t + 1);
  }
}

__global__ __launch_bounds__(TPB, 2) void mlstm(Params p){
  const int wg = blockIdx.x, tid = threadIdx.x;
  const int lane = tid & 63, wave = tid >> 6;
  const int gtid = wg * TPB + tid;
  const int gwave = wg * 8 + wave;
  const int cg = wg & 15, bg = wg >> 4;   // col-group / batch-group roles
  __shared__ float lds[8736];             // D: [8][1028] + xch 512
  __shared__ unsigned sh_base;

  if (tid == 0)
    sh_base = __hip_atomic_load(&g_base2, __ATOMIC_RELAXED, __HIP_MEMORY_SCOPE_SYSTEM);
  __syncthreads();
  const unsigned B = sh_base;

  float* const ws     = p.ws;
  float* const XPp    = ws + O_XPP;
  float* const XPh    = ws + O_XPH;
  float* const htmW   = ws + O_HTMW;
  float* const htWt   = ws + O_HTWT;
  float* const Ws_hs  = ws + O_WSHS;
  float* const h_sT   = ws + O_HST;
  float* const h_s2   = ws + O_HS2;
  float* const h_tT   = ws + O_HTT;
  float* const WihTp  = ws + O_WIHTP;
  float* const WihTh  = ws + O_WIHTH;
  float* const WhhPP  = ws + O_WHHPP;
  float* const WhhPH  = ws + O_WHHPH;
  float* const DW     = ws + O_DW;
  float* const WsT    = ws + O_WST;
  float* const WtT    = ws + O_WTT;
  float* const mWihRT = ws + O_MWIHRT;
  float* const bpP    = ws + O_BPP;
  float* const bpH    = ws + O_BPH;
  float* const bpM    = ws + O_BPM;
  float* const hT2    = ws + O_HT2;
  float* const hmT2   = ws + O_HMT2;
  float* const qbuf   = ws + O_QBUF;
  float* const ak2    = ws + O_AK2;
  float* const hlast  = ws + O_HLAST;

  // ---------------- S0: weight layout transforms ----------------
  for (int idx = gtid; idx < 300*2048; idx += NWG*TPB){
    int e = idx >> 11, jp = idx & 2047;
    int oc = (jp & 3) * 512 + (jp >> 2);
    WihTp[idx] = p.pWih[(size_t)oc*300 + e];
    WihTh[idx] = p.hWih[(size_t)oc*300 + e];
  }
  for (int idx = gtid; idx < 1024*512*2; idx += NWG*TPB){
    int g = idx & 1, k = (idx >> 1) & 511, pp = idx >> 10;
    int hc = pp >> 1, gp = pp & 1, oc = (gp*2+g)*512 + hc;
    WhhPP[idx] = p.pWhh[(size_t)oc*512 + k];
    WhhPH[idx] = p.hWhh[(size_t)oc*512 + k];
  }
  for (int idx = gtid; idx < 1024*1024*2; idx += NWG*TPB){
    int g = idx & 1, k = (idx >> 1) & 1023, pp = idx >> 11;
    int hc = pp >> 1, gp = pp & 1, oc = (gp*2+g)*512 + hc;
    DW[idx] = (k < 512) ? p.mWih[(size_t)oc*1024 + k]
                        : p.mWhh[(size_t)oc*512 + (k - 512)];
  }
  for (int idx = gtid; idx < 512*512; idx += NWG*TPB){
    int k = idx >> 9, h = idx & 511;
    WsT[idx] = p.Ws[(size_t)h*512 + k];
    WtT[idx] = p.Wt[(size_t)h*512 + k];
  }
  for (int idx = gtid; idx < 512*2048; idx += NWG*TPB){
    int k = idx >> 11, jp = idx & 2047;
    int oc = (jp & 3) * 512 + (jp >> 2);
    mWihRT[idx] = p.mWih[(size_t)oc*1024 + 512 + k];
  }
  for (int idx = gtid; idx < 2048; idx += NWG*TPB){
    int oc = (idx & 3) * 512 + (idx >> 2);
    bpP[idx] = p.pb[oc]; bpH[idx] = p.hb[oc]; bpM[idx] = p.mb[oc];
  }
  gbarH();

  // ---------------- S1: XP = embed[tokens] @ WihT + bias ----------------
  for (int task = gwave; task < 6144; task += NWG*8){
    const bool prem = task < 4096;
    int rb, cb;
    if (prem){ cb = task >> 10; rb = task & 1023; }
    else { int t2 = task - 4096; cb = t2 >> 9; rb = t2 & 511; }
    const int r0 = rb * 8;
    const int* toks = prem ? p.premise : p.hyp;
    const float* wT = prem ? WihTp : WihTh;
    const float* bias = prem ? bpP : bpH;
    float* outp = prem ? XPp : XPh;
    const int j0 = cb * 512 + lane * 8;
    const float* xr[8];
    #pragma unroll
    for (int r = 0; r < 8; ++r) xr[r] = p.embed + (size_t)toks[r0 + r] * 300;
    f8v bias8 = *(const f8v*)(bias + j0);
    float acc[8][8];
    #pragma unroll
    for (int r = 0; r < 8; ++r){
      #pragma unroll
      for (int i = 0; i < 8; ++i) acc[r][i] = 0.f;
    }
    for (int e = 0; e < 300; ++e){
      f8v w8 = *(const f8v*)(wT + (size_t)e * 2048 + j0);
      #pragma unroll
      for (int r = 0; r < 8; ++r){
        float xv = xr[r][e];
        #pragma unroll
        for (int i = 0; i < 8; ++i) acc[r][i] += xv * w8[i];
      }
    }
    #pragma unroll
    for (int r = 0; r < 8; ++r){
      f8v o8;
      #pragma unroll
      for (int i = 0; i < 8; ++i) o8[i] = acc[r][i] + bias8[i];
      *(f8v*)(outp + (size_t)(r0 + r) * 2048 + j0) = o8;
    }
  }
  gbarH();

  // ---------------- S2/S3: encoder LSTMs (flag-synced) ----------------
  lstm_enc(wg, tid, lane, cg, bg, 64, XPp, WhhPP, p.plen, hT2, h_sT, h_s2, lds, B);
  lstm_enc(wg, tid, lane, cg, bg, 32, XPh, WhhPH, p.hlen, hT2, h_tT, nullptr, lds, B + 64);
  gbarH();  // flush h_sT/h_s2/h_tT for S4/S5 normal reads

  // ---------------- S4: Ws_hs, htWt, htmW ----------------
  for (int task = gwave; task < 3584; task += NWG*8){
    const float* src; const float* wT; const float* bias; float* outp;
    int rb, cb, cols;
    if (task < 1024){ rb = task;        cb = 0;            src = h_sT; wT = WsT;    bias = nullptr; outp = Ws_hs; cols = 512; }
    else if (task < 1536){ rb = task-1024; cb = 0;         src = h_tT; wT = WtT;    bias = nullptr; outp = htWt;  cols = 512; }
    else { int t2 = task - 1536; cb = t2 >> 9; rb = t2 & 511; src = h_tT; wT = mWihRT; bias = bpM;  outp = htmW;  cols = 2048; }
    const int r0 = rb * 8;
    const int j0 = cb * 512 + lane * 8;
    const float* xr[8];
    #pragma unroll
    for (int r = 0; r < 8; ++r){
      int row = r0 + r;
      xr[r] = src + (size_t)(row >> 7) * 65536 + (row & 127);  // [t][k][b]
    }
    f8v bias8 = {0,0,0,0,0,0,0,0};
    if (bias) bias8 = *(const f8v*)(bias + j0);
    float acc[8][8];
    #pragma unroll
    for (int r = 0; r < 8; ++r){
      #pragma unroll
      for (int i = 0; i < 8; ++i) acc[r][i] = 0.f;
    }
    for (int k = 0; k < 512; ++k){
      f8v w8 = *(const f8v*)(wT + (size_t)k * cols + j0);
      #pragma unroll
      for (int r = 0; r < 8; ++r){
        float xv = xr[r][(size_t)k * 128];
        #pragma unroll
        for (int i = 0; i < 8; ++i) acc[r][i] += xv * w8[i];
      }
    }
    #pragma unroll
    for (int r = 0; r < 8; ++r){
      f8v o8;
      #pragma unroll
      for (int i = 0; i < 8; ++i) o8[i] = acc[r][i] + bias8[i];
      *(f8v*)(outp + (size_t)(r0 + r) * (size_t)cols + j0) = o8;
    }
  }
  gbarH();

  // ---------------- S5: match-LSTM loop (flag-synced) ----------------
  const int b8 = tid & 7, hc32 = (tid >> 3) & 31, gp = tid >> 8;
  const int mb_ = bg*8 + b8, mhc = cg*32 + hc32;
  const float* dwrow = DW + (size_t)(mhc*2 + gp) * 2048;   // [1024][2]
  const int hyplen_b = p.hlen[mb_];
  const int sb = tid >> 6, sk = (tid & 63) * 8;
  float* stage  = lds;             // A: [8][516]; D: [8][1028]
  float* xchA   = lds + 8*516;     // [256]
  float* stage2 = lds;
  float* xch2   = lds + 8*1028;    // [256][2]
  float cm_reg = 0.f, hl_reg = 0.f;
  const unsigned* peerFD = &g_FD[(((unsigned)bg << 4) | (lane & 15)) * 16];
  const unsigned* rowFB  = &g_FB[((unsigned)(bg*8) + (lane & 7)) * 16];

  for (int k = 0; k < 32; ++k){
    const float* hmin  = hmT2 + (size_t)(k & 1) * 65536;
    float*       hmout = hmT2 + (size_t)((k + 1) & 1) * 65536;

    // --- A: q = htWt[k] + h_m @ Wm.T
    // wait: FD bg-peers >= B+k (RAW hm(k), WAR hmout), FB row-blocks >= B+k (WAR qbuf)
    if (lane < 16) waitflag(peerFD, B + k);
    else if (lane < 24) waitflag(&g_FB[((unsigned)(bg*8) + (lane - 16)) * 16], B + k);
    if (k > 0){ // stage h_m slice
      const float* src = hmin + (size_t)(bg*8 + sb)*512 + sk;
      float2 v0 = sysld2(src), v1 = sysld2(src+2), v2 = sysld2(src+4), v3 = sysld2(src+6);
      float* dst = stage + sb*516 + sk;
      float4 w0 = {v0.x, v0.y, v1.x, v1.y};
      float4 w1 = {v2.x, v2.y, v3.x, v3.y};
      *(float4*)dst = w0; *(float4*)(dst+4) = w1;
    }
    __syncthreads();
    {
      const int c32 = (tid >> 3) & 31, half = tid >> 8;
      const int c = cg*32 + c32;
      float a = 0.f;
      if (k > 0){
        const float* hr = stage + b8*516 + half*256;
        const float* wr = p.Wm + (size_t)c*512 + half*256;
        #pragma unroll 2
        for (int kk = 0; kk < 256; kk += 4){
          float4 h4 = *(const float4*)(hr + kk);
          float4 w4 = *(const float4*)(wr + kk);
          a += h4.x*w4.x + h4.y*w4.y + h4.z*w4.z + h4.w*w4.w;
        }
      }
      if (half == 1) xchA[c32*8 + b8] = a;
      __syncthreads();
      if (half == 0){
        float v = a + xchA[c32*8 + b8] + htWt[((size_t)k*128 + mb_)*512 + c];
        sysst(qbuf + (size_t)mb_*512 + c, v);
      }
    }
    __syncthreads();
    if (tid == 0) fbump(&g_FA[wg*16], B + k + 1);

    // --- BC: scores + softmax + a_k (block bb<128 owns one batch element)
    if (wg < 128){
      const int bb = wg;
      // wait: FA producers (cg, bb>>3) >= B+k+1; FD same set >= B+k (WAR ak2)
      if (lane < 16) waitflag(&g_FA[(((unsigned)(bb >> 3) << 4) | lane) * 16], B + k + 1);
      else if (lane < 32) waitflag(&g_FD[(((unsigned)(bb >> 3) << 4) | (lane - 16)) * 16], B + k);
      const float* qb = qbuf + (size_t)bb*512 + lane*8;
      float2 qa = sysld2(qb), qbv = sysld2(qb+2), qc = sysld2(qb+4), qd = sysld2(qb+6);
      float4 q0 = {qa.x, qa.y, qbv.x, qbv.y};
      float4 q1 = {qc.x, qc.y, qd.x, qd.y};
      float4 e0 = *(const float4*)(p.we + lane*8);
      float4 e1 = *(const float4*)(p.we + lane*8 + 4);
      #pragma unroll
      for (int si = 0; si < 8; ++si){
        int s = wave*8 + si;
        const float* wsr = Ws_hs + ((size_t)s*128 + bb)*512 + lane*8;  // L2-warm
        float4 s0 = *(const float4*)wsr;
        float4 s1 = *(const float4*)(wsr + 4);
        float v = tanhf_(s0.x + q0.x)*e0.x + tanhf_(s0.y + q0.y)*e0.y
                + tanhf_(s0.z + q0.z)*e0.z + tanhf_(s0.w + q0.w)*e0.w
                + tanhf_(s1.x + q1.x)*e1.x + tanhf_(s1.y + q1.y)*e1.y
                + tanhf_(s1.z + q1.z)*e1.z + tanhf_(s1.w + q1.w)*e1.w;
        v = wsum(v);
        if (lane == 0) lds[s] = v;
      }
      __syncthreads();
      if (wave == 0){
        float v = lds[lane];
        float m = wmaxr(v);
        float ex = __expf(v - m);
        float sm = wsum(ex);
        lds[64 + lane] = ex / sm;
      }
      __syncthreads();
      {
        float acc = 0.f;
        const float* hsb = h_s2 + (size_t)bb*512 + tid;   // L2-warm
        #pragma unroll 4
        for (int s = 0; s < 64; s += 4){
          float4 al = *(const float4*)(lds + 64 + s);
          acc += al.x * hsb[(size_t)(s+0)*65536]
               + al.y * hsb[(size_t)(s+1)*65536]
               + al.z * hsb[(size_t)(s+2)*65536]
               + al.w * hsb[(size_t)(s+3)*65536];
        }
        sysst(ak2 + (size_t)bb*512 + tid, acc);
      }
      __syncthreads();
      if (tid == 0) fbump(&g_FB[wg*16], B + k + 1);
    }

    // --- D: gates = htmW[k] + [a_k | h_m] @ DW ; cell update
    // wait: FB of this bg's 8 row-blocks >= B+k+1 (RAW ak2)
    if (lane < 8) waitflag(rowFB, B + k + 1);
    { // stage [a_k | h_m] slice (32KB); hm half is zero at k==0
      const int sb2 = tid >> 6, c0 = (tid & 63) * 16;
      float* dst = stage2 + sb2*1028 + c0;
      if (c0 < 512){
        const float* src = ak2 + (size_t)(bg*8 + sb2)*512 + c0;
        #pragma unroll
        for (int i = 0; i < 16; i += 4){
          float2 va = sysld2(src + i), vb = sysld2(src + i + 2);
          float4 w = {va.x, va.y, vb.x, vb.y};
          *(float4*)(dst + i) = w;
        }
      } else if (k > 0){
        const float* src = hmin + (size_t)(bg*8 + sb2)*512 + (c0 - 512);
        #pragma unroll
        for (int i = 0; i < 16; i += 4){
          float2 va = sysld2(src + i), vb = sysld2(src + i + 2);
          float4 w = {va.x, va.y, vb.x, vb.y};
          *(float4*)(dst + i) = w;
        }
      } else {
        float4 z = {0.f, 0.f, 0.f, 0.f};
        #pragma unroll
        for (int i = 0; i < 16; i += 4) *(float4*)(dst + i) = z;
      }
    }
    __syncthreads();
    {
      float a0 = 0.f, a1 = 0.f;
      const float* hr = stage2 + b8*1028;
      #pragma unroll 2
      for (int kk = 0; kk < 1024; kk += 4){
        float4 h4 = *(const float4*)(hr + kk);
        float4 wA = *(const float4*)(dwrow + kk*2);
        float4 wB = *(const float4*)(dwrow + kk*2 + 4);
        a0 += h4.x*wA.x + h4.y*wA.z + h4.z*wB.x + h4.w*wB.z;
        a1 += h4.x*wA.y + h4.y*wA.w + h4.z*wB.y + h4.w*wB.w;
      }
      float2 xg = *(const float2*)(htmW + ((size_t)k*128 + mb_)*2048 + mhc*4 + gp*2);
      a0 += xg.x; a1 += xg.y;
      if (gp == 1){ xch2[(b8*32+hc32)*2+0] = a0; xch2[(b8*32+hc32)*2+1] = a1; }
      __syncthreads();
      if (gp == 0){
        float gg = xch2[(b8*32+hc32)*2+0], go = xch2[(b8*32+hc32)*2+1];
        float iv = sigf(a0), fv = sigf(a1), gv = tanhf_(gg), ov = sigf(go);
        cm_reg = fv * cm_reg + iv * gv;
        float hv = ov * tanhf_(cm_reg);
        sysst(hmout + (size_t)mb_*512 + mhc, hv);
        if (k + 1 == hyplen_b) hl_reg = hv;
      }
    }
    __syncthreads();
    if (tid == 0) fbump(&g_FD[wg*16], B + k + 1);
  }

  if (gp == 0) hlast[(size_t)mb_*512 + mhc] = hl_reg;
  gbarH();

  // Reset all flags to a common base for the next launch (device globals are
  // never re-poisoned; all blocks are past all polls after gbarH).
  if (tid == 0){
    fbump(&g_FE[wg*16], B + 4096);
    fbump(&g_FA[wg*16], B + 4096);
    fbump(&g_FB[wg*16], B + 4096);
    fbump(&g_FD[wg*16], B + 4096);
    if (wg == 0)
      __hip_atomic_store(&g_base2, B + 4096, __ATOMIC_RELAXED, __HIP_MEMORY_SCOPE_SYSTEM);
  }

  // ---------------- S6: fc on block 0 ----------------
  if (wg == 0){
    for (int o = wave; o < 384; o += 8){
      int bb = o / 3, cls = o - bb*3;
      const float* hr = hlast + (size_t)bb*512 + lane*8;
      const float* wr = p.fcW + (size_t)cls*512 + lane*8;
      float4 h0 = *(const float4*)hr, h1 = *(const float4*)(hr + 4);
      float4 w0 = *(const float4*)wr, w1 = *(const float4*)(wr + 4);
      float v = h0.x*w0.x + h0.y*w0.y + h0.z*w0.z + h0.w*w0.w
              + h1.x*w1.x + h1.y*w1.y + h1.z*w1.z + h1.w*w1.w;
      v = wsum(v);
      if (lane == 0) p.out[o] = v + p.fcb[cls];
    }
  }
}

extern "C" void kernel_launch(void* const* d_in, const int* in_sizes, int n_in,
                              void* d_out, int out_size, void* d_ws, size_t ws_size,
                              hipStream_t stream) {
  if (ws_size < WS_FLOATS * sizeof(float)) return;  // fail clean, not OOB
  Params prm;
  prm.premise = (const int*)d_in[0];
  prm.plen    = (const int*)d_in[1];
  prm.hyp     = (const int*)d_in[2];
  prm.hlen    = (const int*)d_in[3];
  prm.embed   = (const float*)d_in[4];
  prm.pWih    = (const float*)d_in[5];
  prm.pWhh    = (const float*)d_in[6];
  prm.pb      = (const float*)d_in[7];
  prm.hWih    = (const float*)d_in[8];
  prm.hWhh    = (const float*)d_in[9];
  prm.hb      = (const float*)d_in[10];
  prm.mWih    = (const float*)d_in[11];
  prm.mWhh    = (const float*)d_in[12];
  prm.mb      = (const float*)d_in[13];
  prm.we      = (const float*)d_in[14];
  prm.Ws      = (const float*)d_in[15];
  prm.Wt      = (const float*)d_in[16];
  prm.Wm      = (const float*)d_in[17];
  prm.fcW     = (const float*)d_in[18];
  prm.fcb     = (const float*)d_in[19];
  prm.out     = (float*)d_out;
  prm.ws      = (float*)d_ws;
  mlstm<<<dim3(NWG), dim3(TPB), 0, stream>>>(prm);
}

// Round 5
// 4305.391 us; speedup vs baseline: 3.1502x; 1.0371x over previous
//
#include <hip/hip_runtime.h>

// MatchLSTM, fp32, round 5: split into 6 dispatches for per-phase rocprof
// timing. Kernel boundaries replace heavy barriers (HSA dispatch ordering).
// Persistent phases (encP/encH/match) keep R4's producer->consumer epoch
// flags, but only wave 0 polls (8x less flag-line traffic), then
// __syncthreads releases the block. Flag base = each block's own flag value
// at kernel entry (monotone across graph replays, no reset needed).

#define NWG 256
#define TPB 512

typedef float f8v __attribute__((ext_vector_type(8)));

// ---- workspace layout (float offsets) ----
#define O_XPP      0ull          // [64][128][2048] premise input proj (+bias)
#define O_HTMW     0ull          // overlay after encoders: [32][128][2048]
#define O_HTWT     8388608ull    // [32][128][512]
#define O_WSHS     10485760ull   // [64][128][512]
#define O_XPH      16777216ull   // [32][128][2048]
#define O_HST      25165824ull   // [64][512][128]  masked premise h (k-major)
#define O_HS2      29360128ull   // [64][128][512]  masked premise h (h-major)
#define O_HTT      33554432ull   // [32][512][128]  masked hyp h (k-major)
#define O_WIHTP    35651584ull   // [300][2048] perm
#define O_WIHTH    36265984ull
#define O_WHHPP    36880384ull   // [1024 pair-rows][512 k][2] premise Whh
#define O_WHHPH    37928960ull
#define O_DW       38977536ull   // [1024 pair-rows][1024 k][2] match (mWihL | mWhh)
#define O_WST      41074688ull   // [512][512] k-major
#define O_WTT      41336832ull
#define O_MWIHRT   41598976ull   // [512][2048] perm
#define O_BPP      42647552ull   // [2048] perm biases
#define O_BPH      42649600ull
#define O_BPM      42651648ull
#define O_HT2      42653696ull   // [2][128][512] encoder h double buffer (coherent)
#define O_HMT2     42784768ull   // [2][128][512] match h double buffer (coherent)
#define O_QBUF     42915840ull   // [128][512] (coherent)
#define O_AK2      42981376ull   // [128][512] (coherent)
#define O_HLAST    43046912ull   // [128][512] (coherent)
#define WS_FLOATS  43112448ull

__device__ unsigned g_FE[NWG * 16];      // encoder step flags (64B padded)
__device__ unsigned g_FA[NWG * 16];      // match A flags
__device__ unsigned g_FB[NWG * 16];      // match BC flags
__device__ unsigned g_FD[NWG * 16];      // match D flags

struct Params {
  const int* premise; const int* plen; const int* hyp; const int* hlen;
  const float* embed;
  const float* pWih; const float* pWhh; const float* pb;
  const float* hWih; const float* hWhh; const float* hb;
  const float* mWih; const float* mWhh; const float* mb;
  const float* we; const float* Ws; const float* Wt; const float* Wm;
  const float* fcW; const float* fcb;
  float* out; float* ws;
};

// ---- coherent (system-scope, L2-bypassing) accessors for mutable state ----
__device__ __forceinline__ float2 sysld2(const float* p){
  unsigned long long u = __hip_atomic_load((const unsigned long long*)p,
      __ATOMIC_RELAXED, __HIP_MEMORY_SCOPE_SYSTEM);
  union { unsigned long long u; float2 f; } c; c.u = u; return c.f;
}
__device__ __forceinline__ void sysst(float* p, float v){
  union { float f; unsigned u; } c; c.f = v;
  __hip_atomic_store((unsigned*)p, c.u, __ATOMIC_RELAXED, __HIP_MEMORY_SCOPE_SYSTEM);
}
__device__ __forceinline__ void fbump(unsigned* a, unsigned v){
  __hip_atomic_store(a, v, __ATOMIC_RELAXED, __HIP_MEMORY_SCOPE_SYSTEM);
}
__device__ __forceinline__ unsigned fread_(const unsigned* a){
  return __hip_atomic_load(a, __ATOMIC_RELAXED, __HIP_MEMORY_SCOPE_SYSTEM);
}
__device__ __forceinline__ void waitflag(const unsigned* a, unsigned tgt){
  while ((int)(fread_(a) - tgt) < 0) __builtin_amdgcn_s_sleep(2);
}

__device__ __forceinline__ float sigf(float x){ return 1.0f/(1.0f + __expf(-x)); }
__device__ __forceinline__ float tanhf_(float x){ return 2.0f/(1.0f + __expf(-2.0f*x)) - 1.0f; }

__device__ __forceinline__ float wsum(float v){
  #pragma unroll
  for (int o = 32; o > 0; o >>= 1) v += __shfl_xor(v, o, 64);
  return v;
}
__device__ __forceinline__ float wmaxr(float v){
  #pragma unroll
  for (int o = 32; o > 0; o >>= 1) v = fmaxf(v, __shfl_xor(v, o, 64));
  return v;
}

// ================= S0: weight layout transforms (grid 1024) =================
__global__ __launch_bounds__(TPB) void k_s0(Params p){
  const int tid0 = blockIdx.x * TPB + threadIdx.x;
  const int stride = gridDim.x * TPB;
  float* const ws = p.ws;
  float* const WihTp  = ws + O_WIHTP;
  float* const WihTh  = ws + O_WIHTH;
  float* const WhhPP  = ws + O_WHHPP;
  float* const WhhPH  = ws + O_WHHPH;
  float* const DW     = ws + O_DW;
  float* const WsT    = ws + O_WST;
  float* const WtT    = ws + O_WTT;
  float* const mWihRT = ws + O_MWIHRT;
  float* const bpP    = ws + O_BPP;
  float* const bpH    = ws + O_BPH;
  float* const bpM    = ws + O_BPM;

  for (int idx = tid0; idx < 300*2048; idx += stride){
    int e = idx >> 11, jp = idx & 2047;
    int oc = (jp & 3) * 512 + (jp >> 2);
    WihTp[idx] = p.pWih[(size_t)oc*300 + e];
    WihTh[idx] = p.hWih[(size_t)oc*300 + e];
  }
  for (int idx = tid0; idx < 1024*512*2; idx += stride){
    int g = idx & 1, k = (idx >> 1) & 511, pp = idx >> 10;
    int hc = pp >> 1, gp = pp & 1, oc = (gp*2+g)*512 + hc;
    WhhPP[idx] = p.pWhh[(size_t)oc*512 + k];
    WhhPH[idx] = p.hWhh[(size_t)oc*512 + k];
  }
  for (int idx = tid0; idx < 1024*1024*2; idx += stride){
    int g = idx & 1, k = (idx >> 1) & 1023, pp = idx >> 11;
    int hc = pp >> 1, gp = pp & 1, oc = (gp*2+g)*512 + hc;
    DW[idx] = (k < 512) ? p.mWih[(size_t)oc*1024 + k]
                        : p.mWhh[(size_t)oc*512 + (k - 512)];
  }
  for (int idx = tid0; idx < 512*512; idx += stride){
    int k = idx >> 9, h = idx & 511;
    WsT[idx] = p.Ws[(size_t)h*512 + k];
    WtT[idx] = p.Wt[(size_t)h*512 + k];
  }
  for (int idx = tid0; idx < 512*2048; idx += stride){
    int k = idx >> 11, jp = idx & 2047;
    int oc = (jp & 3) * 512 + (jp >> 2);
    mWihRT[idx] = p.mWih[(size_t)oc*1024 + 512 + k];
  }
  for (int idx = tid0; idx < 2048; idx += stride){
    int oc = (idx & 3) * 512 + (idx >> 2);
    bpP[idx] = p.pb[oc]; bpH[idx] = p.hb[oc]; bpM[idx] = p.mb[oc];
  }
}

// ================= S1: XP = embed[tokens] @ WihT + bias (grid 768) ==========
__global__ __launch_bounds__(TPB) void k_s1(Params p){
  const int tid = threadIdx.x, lane = tid & 63, wave = tid >> 6;
  const int gwave = blockIdx.x * 8 + wave;
  const int wstride = gridDim.x * 8;
  float* const ws = p.ws;
  float* const XPp   = ws + O_XPP;
  float* const XPh   = ws + O_XPH;
  const float* WihTp = ws + O_WIHTP;
  const float* WihTh = ws + O_WIHTH;
  const float* bpP   = ws + O_BPP;
  const float* bpH   = ws + O_BPH;

  for (int task = gwave; task < 6144; task += wstride){
    const bool prem = task < 4096;
    int rb, cb;
    if (prem){ cb = task >> 10; rb = task & 1023; }
    else { int t2 = task - 4096; cb = t2 >> 9; rb = t2 & 511; }
    const int r0 = rb * 8;
    const int* toks = prem ? p.premise : p.hyp;
    const float* wT = prem ? WihTp : WihTh;
    const float* bias = prem ? bpP : bpH;
    float* outp = prem ? XPp : XPh;
    const int j0 = cb * 512 + lane * 8;
    const float* xr[8];
    #pragma unroll
    for (int r = 0; r < 8; ++r) xr[r] = p.embed + (size_t)toks[r0 + r] * 300;
    f8v bias8 = *(const f8v*)(bias + j0);
    float acc[8][8];
    #pragma unroll
    for (int r = 0; r < 8; ++r){
      #pragma unroll
      for (int i = 0; i < 8; ++i) acc[r][i] = 0.f;
    }
    for (int e = 0; e < 300; ++e){
      f8v w8 = *(const f8v*)(wT + (size_t)e * 2048 + j0);
      #pragma unroll
      for (int r = 0; r < 8; ++r){
        float xv = xr[r][e];
        #pragma unroll
        for (int i = 0; i < 8; ++i) acc[r][i] += xv * w8[i];
      }
    }
    #pragma unroll
    for (int r = 0; r < 8; ++r){
      f8v o8;
      #pragma unroll
      for (int i = 0; i < 8; ++i) o8[i] = acc[r][i] + bias8[i];
      *(f8v*)(outp + (size_t)(r0 + r) * 2048 + j0) = o8;
    }
  }
}

// ================= encoder LSTM phase (persistent, grid 256) ================
// Block = (cg: 32 h-cols, bg: 8 batch). Thread (b8,hc32,gp) owns gates
// {gp*2,gp*2+1}. Only wave 0 polls the 16 bg-peer flags; t==0 skips h.
__device__ void lstm_enc(int wg, int tid, int cg, int bg, int T,
    const float* __restrict__ XP, const float* __restrict__ WPair,
    const int* __restrict__ lens, float* hbuf,
    float* __restrict__ houtT, float* __restrict__ hout2, float* lds,
    unsigned B)
{
  const int b8 = tid & 7, hc32 = (tid >> 3) & 31, gp = tid >> 8;
  const int b = bg*8 + b8, hc = cg*32 + hc32;
  const float* wrow = WPair + (size_t)(hc*2 + gp) * 1024;   // [512][2]
  const int mylen = lens[b];
  const int sb = tid >> 6, sk = (tid & 63) * 8;
  float* stage = lds;            // [8][516] padded
  float* xch   = lds + 8*516;    // [256][2]
  float c_reg = 0.f;

  for (int t = 0; t < T; ++t){
    const float* hin  = hbuf + (size_t)(t & 1) * 65536;
    float*       hout = hbuf + (size_t)((t + 1) & 1) * 65536;
    if (t > 0){
      if (tid < 16) waitflag(&g_FE[(unsigned)(bg*16 + tid)*16], B + t);
      __syncthreads();
      const float* src = hin + (size_t)(bg*8 + sb)*512 + sk;
      float2 v0 = sysld2(src), v1 = sysld2(src+2), v2 = sysld2(src+4), v3 = sysld2(src+6);
      float* dst = stage + sb*516 + sk;
      float4 w0 = {v0.x, v0.y, v1.x, v1.y};
      float4 w1 = {v2.x, v2.y, v3.x, v3.y};
      *(float4*)dst = w0; *(float4*)(dst+4) = w1;
    }
    __syncthreads();
    float a0 = 0.f, a1 = 0.f;
    if (t > 0){
      const float* hr = stage + b8*516;
      #pragma unroll 2
      for (int k = 0; k < 512; k += 4){
        float4 h4 = *(const float4*)(hr + k);
        float4 wA = *(const float4*)(wrow + k*2);
        float4 wB = *(const float4*)(wrow + k*2 + 4);
        a0 += h4.x*wA.x + h4.y*wA.z + h4.z*wB.x + h4.w*wB.z;
        a1 += h4.x*wA.y + h4.y*wA.w + h4.z*wB.y + h4.w*wB.w;
      }
    }
    float2 xg = *(const float2*)(XP + ((size_t)t*128 + b)*2048 + hc*4 + gp*2);
    a0 += xg.x; a1 += xg.y;
    if (gp == 1){ xch[(b8*32+hc32)*2+0] = a0; xch[(b8*32+hc32)*2+1] = a1; }
    __syncthreads();
    if (gp == 0){
      float gg = xch[(b8*32+hc32)*2+0], go = xch[(b8*32+hc32)*2+1];
      float iv = sigf(a0), fv = sigf(a1), gv = tanhf_(gg), ov = sigf(go);
      c_reg = fv * c_reg + iv * gv;
      float hv = ov * tanhf_(c_reg);
      sysst(hout + (size_t)b*512 + hc, hv);          // coherent recurrence state
      float hm = (t < mylen) ? hv : 0.f;             // masked outputs (normal)
      houtT[((size_t)t*512 + hc)*128 + b] = hm;
      if (hout2) hout2[((size_t)t*128 + b)*512 + hc] = hm;
    }
    __syncthreads();                                  // drains all waves' vmem
    if (tid == 0) fbump(&g_FE[wg*16], B + t + 1);
  }
}

__global__ __launch_bounds__(TPB, 2) void k_encp(Params p){
  const int wg = blockIdx.x, tid = threadIdx.x;
  const int cg = wg & 15, bg = wg >> 4;
  __shared__ float lds[4640];
  __shared__ unsigned shB;
  if (tid == 0) shB = fread_(&g_FE[wg*16]);
  __syncthreads();
  lstm_enc(wg, tid, cg, bg, 64, p.ws + O_XPP, p.ws + O_WHHPP, p.plen,
           p.ws + O_HT2, p.ws + O_HST, p.ws + O_HS2, lds, shB);
}
__global__ __launch_bounds__(TPB, 2) void k_ench(Params p){
  const int wg = blockIdx.x, tid = threadIdx.x;
  const int cg = wg & 15, bg = wg >> 4;
  __shared__ float lds[4640];
  __shared__ unsigned shB;
  if (tid == 0) shB = fread_(&g_FE[wg*16]);
  __syncthreads();
  lstm_enc(wg, tid, cg, bg, 32, p.ws + O_XPH, p.ws + O_WHHPH, p.hlen,
           p.ws + O_HT2, p.ws + O_HTT, nullptr, lds, shB);
}

// ================= S4: Ws_hs, htWt, htmW (grid 448) =========================
__global__ __launch_bounds__(TPB) void k_s4(Params p){
  const int tid = threadIdx.x, lane = tid & 63, wave = tid >> 6;
  const int gwave = blockIdx.x * 8 + wave;
  const int wstride = gridDim.x * 8;
  float* const ws = p.ws;
  const float* h_sT   = ws + O_HST;
  const float* h_tT   = ws + O_HTT;
  const float* WsT    = ws + O_WST;
  const float* WtT    = ws + O_WTT;
  const float* mWihRT = ws + O_MWIHRT;
  const float* bpM    = ws + O_BPM;
  float* const Ws_hs  = ws + O_WSHS;
  float* const htWt   = ws + O_HTWT;
  float* const htmW   = ws + O_HTMW;

  for (int task = gwave; task < 3584; task += wstride){
    const float* src; const float* wT; const float* bias; float* outp;
    int rb, cb, cols;
    if (task < 1024){ rb = task;        cb = 0;            src = h_sT; wT = WsT;    bias = nullptr; outp = Ws_hs; cols = 512; }
    else if (task < 1536){ rb = task-1024; cb = 0;         src = h_tT; wT = WtT;    bias = nullptr; outp = htWt;  cols = 512; }
    else { int t2 = task - 1536; cb = t2 >> 9; rb = t2 & 511; src = h_tT; wT = mWihRT; bias = bpM;  outp = htmW;  cols = 2048; }
    const int r0 = rb * 8;
    const int j0 = cb * 512 + lane * 8;
    const float* xr[8];
    #pragma unroll
    for (int r = 0; r < 8; ++r){
      int row = r0 + r;
      xr[r] = src + (size_t)(row >> 7) * 65536 + (row & 127);  // [t][k][b]
    }
    f8v bias8 = {0,0,0,0,0,0,0,0};
    if (bias) bias8 = *(const f8v*)(bias + j0);
    float acc[8][8];
    #pragma unroll
    for (int r = 0; r < 8; ++r){
      #pragma unroll
      for (int i = 0; i < 8; ++i) acc[r][i] = 0.f;
    }
    for (int k = 0; k < 512; ++k){
      f8v w8 = *(const f8v*)(wT + (size_t)k * cols + j0);
      #pragma unroll
      for (int r = 0; r < 8; ++r){
        float xv = xr[r][(size_t)k * 128];
        #pragma unroll
        for (int i = 0; i < 8; ++i) acc[r][i] += xv * w8[i];
      }
    }
    #pragma unroll
    for (int r = 0; r < 8; ++r){
      f8v o8;
      #pragma unroll
      for (int i = 0; i < 8; ++i) o8[i] = acc[r][i] + bias8[i];
      *(f8v*)(outp + (size_t)(r0 + r) * (size_t)cols + j0) = o8;
    }
  }
}

// ================= match-LSTM loop + fc (persistent, grid 256) ==============
__global__ __launch_bounds__(TPB, 2) void k_match(Params p){
  const int wg = blockIdx.x, tid = threadIdx.x;
  const int lane = tid & 63, wave = tid >> 6;
  const int cg = wg & 15, bg = wg >> 4;
  __shared__ float lds[8736];
  __shared__ unsigned shB;
  if (tid == 0) shB = fread_(&g_FD[wg*16]);
  __syncthreads();
  const unsigned B = shB;

  float* const ws = p.ws;
  const float* htmW  = ws + O_HTMW;
  const float* htWt  = ws + O_HTWT;
  const float* Ws_hs = ws + O_WSHS;
  const float* h_s2  = ws + O_HS2;
  const float* DW    = ws + O_DW;
  float* const hmT2  = ws + O_HMT2;
  float* const qbuf  = ws + O_QBUF;
  float* const ak2   = ws + O_AK2;
  float* const hlast = ws + O_HLAST;

  const int b8 = tid & 7, hc32 = (tid >> 3) & 31, gp = tid >> 8;
  const int mb_ = bg*8 + b8, mhc = cg*32 + hc32;
  const float* dwrow = DW + (size_t)(mhc*2 + gp) * 2048;   // [1024][2]
  const int hyplen_b = p.hlen[mb_];
  const int sb = tid >> 6, sk = (tid & 63) * 8;
  float* stage  = lds;             // A: [8][516]; D: [8][1028]
  float* xchA   = lds + 8*516;     // [256]
  float* stage2 = lds;
  float* xch2   = lds + 8*1028;    // [256][2]
  float cm_reg = 0.f, hl_reg = 0.f;

  for (int k = 0; k < 32; ++k){
    const float* hmin  = hmT2 + (size_t)(k & 1) * 65536;
    float*       hmout = hmT2 + (size_t)((k + 1) & 1) * 65536;

    // --- A: q = htWt[k] + h_m @ Wm.T
    // wait: FD bg-peers >= B+k (RAW hm, WAR hmout); FB rows >= B+k (WAR qbuf)
    if (tid < 16) waitflag(&g_FD[(unsigned)(bg*16 + tid)*16], B + k);
    else if (tid < 24) waitflag(&g_FB[(unsigned)(bg*8 + tid - 16)*16], B + k);
    __syncthreads();
    if (k > 0){ // stage h_m slice
      const float* src = hmin + (size_t)(bg*8 + sb)*512 + sk;
      float2 v0 = sysld2(src), v1 = sysld2(src+2), v2 = sysld2(src+4), v3 = sysld2(src+6);
      float* dst = stage + sb*516 + sk;
      float4 w0 = {v0.x, v0.y, v1.x, v1.y};
      float4 w1 = {v2.x, v2.y, v3.x, v3.y};
      *(float4*)dst = w0; *(float4*)(dst+4) = w1;
    }
    __syncthreads();
    {
      const int c32 = (tid >> 3) & 31, half = tid >> 8;
      const int c = cg*32 + c32;
      float a = 0.f;
      if (k > 0){
        const float* hr = stage + b8*516 + half*256;
        const float* wr = p.Wm + (size_t)c*512 + half*256;
        #pragma unroll 2
        for (int kk = 0; kk < 256; kk += 4){
          float4 h4 = *(const float4*)(hr + kk);
          float4 w4 = *(const float4*)(wr + kk);
          a += h4.x*w4.x + h4.y*w4.y + h4.z*w4.z + h4.w*w4.w;
        }
      }
      if (half == 1) xchA[c32*8 + b8] = a;
      __syncthreads();
      if (half == 0){
        float v = a + xchA[c32*8 + b8] + htWt[((size_t)k*128 + mb_)*512 + c];
        sysst(qbuf + (size_t)mb_*512 + c, v);
      }
    }
    __syncthreads();
    if (tid == 0) fbump(&g_FA[wg*16], B + k + 1);

    // --- BC: scores + softmax + a_k (block bb<128 owns one batch element)
    if (wg < 128){
      const int bb = wg;
      if (tid < 16) waitflag(&g_FA[(unsigned)((bb >> 3)*16 + tid)*16], B + k + 1);
      else if (tid < 32) waitflag(&g_FD[(unsigned)((bb >> 3)*16 + tid - 16)*16], B + k);
      __syncthreads();
      const float* qb = qbuf + (size_t)bb*512 + lane*8;
      float2 qa = sysld2(qb), qbv = sysld2(qb+2), qc = sysld2(qb+4), qd = sysld2(qb+6);
      float4 q0 = {qa.x, qa.y, qbv.x, qbv.y};
      float4 q1 = {qc.x, qc.y, qd.x, qd.y};
      float4 e0 = *(const float4*)(p.we + lane*8);
      float4 e1 = *(const float4*)(p.we + lane*8 + 4);
      #pragma unroll
      for (int si = 0; si < 8; ++si){
        int s = wave*8 + si;
        const float* wsr = Ws_hs + ((size_t)s*128 + bb)*512 + lane*8;  // L2-warm
        float4 s0 = *(const float4*)wsr;
        float4 s1 = *(const float4*)(wsr + 4);
        float v = tanhf_(s0.x + q0.x)*e0.x + tanhf_(s0.y + q0.y)*e0.y
                + tanhf_(s0.z + q0.z)*e0.z + tanhf_(s0.w + q0.w)*e0.w
                + tanhf_(s1.x + q1.x)*e1.x + tanhf_(s1.y + q1.y)*e1.y
                + tanhf_(s1.z + q1.z)*e1.z + tanhf_(s1.w + q1.w)*e1.w;
        v = wsum(v);
        if (lane == 0) lds[s] = v;
      }
      __syncthreads();
      if (wave == 0){
        float v = lds[lane];
        float m = wmaxr(v);
        float ex = __expf(v - m);
        float sm = wsum(ex);
        lds[64 + lane] = ex / sm;
      }
      __syncthreads();
      {
        float acc = 0.f;
        const float* hsb = h_s2 + (size_t)bb*512 + tid;   // L2-warm
        #pragma unroll 4
        for (int s = 0; s < 64; s += 4){
          float4 al = *(const float4*)(lds + 64 + s);
          acc += al.x * hsb[(size_t)(s+0)*65536]
               + al.y * hsb[(size_t)(s+1)*65536]
               + al.z * hsb[(size_t)(s+2)*65536]
               + al.w * hsb[(size_t)(s+3)*65536];
        }
        sysst(ak2 + (size_t)bb*512 + tid, acc);
      }
      __syncthreads();
      if (tid == 0) fbump(&g_FB[wg*16], B + k + 1);
    }

    // --- D: gates = htmW[k] + [a_k | h_m] @ DW ; cell update
    if (tid < 8) waitflag(&g_FB[(unsigned)(bg*8 + tid)*16], B + k + 1);
    __syncthreads();
    { // stage [a_k | h_m] slice (32KB); hm half is zero at k==0
      const int sb2 = tid >> 6, c0 = (tid & 63) * 16;
      float* dst = stage2 + sb2*1028 + c0;
      if (c0 < 512){
        const float* src = ak2 + (size_t)(bg*8 + sb2)*512 + c0;
        #pragma unroll
        for (int i = 0; i < 16; i += 4){
          float2 va = sysld2(src + i), vb = sysld2(src + i + 2);
          float4 w = {va.x, va.y, vb.x, vb.y};
          *(float4*)(dst + i) = w;
        }
      } else if (k > 0){
        const float* src = hmin + (size_t)(bg*8 + sb2)*512 + (c0 - 512);
        #pragma unroll
        for (int i = 0; i < 16; i += 4){
          float2 va = sysld2(src + i), vb = sysld2(src + i + 2);
          float4 w = {va.x, va.y, vb.x, vb.y};
          *(float4*)(dst + i) = w;
        }
      } else {
        float4 z = {0.f, 0.f, 0.f, 0.f};
        #pragma unroll
        for (int i = 0; i < 16; i += 4) *(float4*)(dst + i) = z;
      }
    }
    __syncthreads();
    {
      float a0 = 0.f, a1 = 0.f;
      const float* hr = stage2 + b8*1028;
      #pragma unroll 2
      for (int kk = 0; kk < 1024; kk += 4){
        float4 h4 = *(const float4*)(hr + kk);
        float4 wA = *(const float4*)(dwrow + kk*2);
        float4 wB = *(const float4*)(dwrow + kk*2 + 4);
        a0 += h4.x*wA.x + h4.y*wA.z + h4.z*wB.x + h4.w*wB.z;
        a1 += h4.x*wA.y + h4.y*wA.w + h4.z*wB.y + h4.w*wB.w;
      }
      float2 xg = *(const float2*)(htmW + ((size_t)k*128 + mb_)*2048 + mhc*4 + gp*2);
      a0 += xg.x; a1 += xg.y;
      if (gp == 1){ xch2[(b8*32+hc32)*2+0] = a0; xch2[(b8*32+hc32)*2+1] = a1; }
      __syncthreads();
      if (gp == 0){
        float gg = xch2[(b8*32+hc32)*2+0], go = xch2[(b8*32+hc32)*2+1];
        float iv = sigf(a0), fv = sigf(a1), gv = tanhf_(gg), ov = sigf(go);
        cm_reg = fv * cm_reg + iv * gv;
        float hv = ov * tanhf_(cm_reg);
        sysst(hmout + (size_t)mb_*512 + mhc, hv);
        if (k + 1 == hyplen_b) hl_reg = hv;
      }
    }
    __syncthreads();
    if (tid == 0) fbump(&g_FD[wg*16], B + k + 1);
  }

  // publish hlast, then advance all own flags to a common final epoch
  if (gp == 0) sysst(hlast + (size_t)mb_*512 + mhc, hl_reg);
  __syncthreads();
  if (tid == 0){
    fbump(&g_FD[wg*16], B + 40);
    fbump(&g_FA[wg*16], B + 40);
    fbump(&g_FB[wg*16], B + 40);
  }

  // ---------------- fc on block 0 ----------------
  if (wg == 0){
    if (tid < NWG) waitflag(&g_FD[(unsigned)tid*16], B + 40);
    __syncthreads();
    for (int o = wave; o < 384; o += 8){
      int bb = o / 3, cls = o - bb*3;
      const float* hr = hlast + (size_t)bb*512 + lane*8;
      const float* wr = p.fcW + (size_t)cls*512 + lane*8;
      float2 ha = sysld2(hr), hb = sysld2(hr+2), hc2 = sysld2(hr+4), hd = sysld2(hr+6);
      float4 w0 = *(const float4*)wr, w1 = *(const float4*)(wr + 4);
      float v = ha.x*w0.x + ha.y*w0.y + hb.x*w0.z + hb.y*w0.w
              + hc2.x*w1.x + hc2.y*w1.y + hd.x*w1.z + hd.y*w1.w;
      v = wsum(v);
      if (lane == 0) p.out[o] = v + p.fcb[cls];
    }
  }
}

extern "C" void kernel_launch(void* const* d_in, const int* in_sizes, int n_in,
                              void* d_out, int out_size, void* d_ws, size_t ws_size,
                              hipStream_t stream) {
  if (ws_size < WS_FLOATS * sizeof(float)) return;  // fail clean, not OOB
  Params prm;
  prm.premise = (const int*)d_in[0];
  prm.plen    = (const int*)d_in[1];
  prm.hyp     = (const int*)d_in[2];
  prm.hlen    = (const int*)d_in[3];
  prm.embed   = (const float*)d_in[4];
  prm.pWih    = (const float*)d_in[5];
  prm.pWhh    = (const float*)d_in[6];
  prm.pb      = (const float*)d_in[7];
  prm.hWih    = (const float*)d_in[8];
  prm.hWhh    = (const float*)d_in[9];
  prm.hb      = (const float*)d_in[10];
  prm.mWih    = (const float*)d_in[11];
  prm.mWhh    = (const float*)d_in[12];
  prm.mb      = (const float*)d_in[13];
  prm.we      = (const float*)d_in[14];
  prm.Ws      = (const float*)d_in[15];
  prm.Wt      = (const float*)d_in[16];
  prm.Wm      = (const float*)d_in[17];
  prm.fcW     = (const float*)d_in[18];
  prm.fcb     = (const float*)d_in[19];
  prm.out     = (float*)d_out;
  prm.ws      = (float*)d_ws;

  k_s0   <<<dim3(1024), dim3(TPB), 0, stream>>>(prm);
  k_s1   <<<dim3(768),  dim3(TPB), 0, stream>>>(prm);
  k_encp <<<dim3(NWG),  dim3(TPB), 0, stream>>>(prm);
  k_ench <<<dim3(NWG),  dim3(TPB), 0, stream>>>(prm);
  k_s4   <<<dim3(448),  dim3(TPB), 0, stream>>>(prm);
  k_match<<<dim3(NWG),  dim3(TPB), 0, stream>>>(prm);
}